// Round 1
// baseline (984.968 us; speedup 1.0000x reference)
//
#include <hip/hip_runtime.h>

// GraphSAGE 2-layer forward on MI355X.
// Strategy:
//  - Build CSR (dst -> list of src) once per call: histogram + scan + fill.
//  - Layer 1 (transform-first): xl = x@w1_l, xr = x@w1_r + b1 (VALU matmuls,
//    weights in LDS), then wave-per-node gather-mean over xl + relu -> h.
//  - Layer 2 (transform-first, 8x gather reduction): hl = h@w2_l,
//    hr = h@w2_r + b2 (16-wide), then wave-per-node gather-mean over hl with
//    fused log_softmax epilogue via shfl reductions.
// No fp32 atomics anywhere; no MFMA (no fp32-input MFMA on CDNA4, bf16 cast
// too risky for log_softmax accuracy).

#define NN 100000
#define NE 1600000
#define D  128
#define NC 16

__device__ __forceinline__ int gtid() { return blockIdx.x * blockDim.x + threadIdx.x; }

// ---------------- CSR build ----------------

__global__ __launch_bounds__(256) void count_k(const int* __restrict__ dstv,
                                               int* __restrict__ counts) {
    for (int i = gtid(); i < NE; i += gridDim.x * blockDim.x)
        atomicAdd(&counts[dstv[i]], 1);
}

__global__ __launch_bounds__(1024) void scanA_k(const int* __restrict__ counts,
                                                int* __restrict__ bsum) {
    __shared__ int red[16];
    int i = blockIdx.x * 1024 + threadIdx.x;
    int v = (i < NN) ? counts[i] : 0;
#pragma unroll
    for (int o = 32; o > 0; o >>= 1) v += __shfl_down(v, o);
    int w = threadIdx.x >> 6, lane = threadIdx.x & 63;
    if (lane == 0) red[w] = v;
    __syncthreads();
    if (threadIdx.x == 0) {
        int s = 0;
        for (int j = 0; j < 16; j++) s += red[j];
        bsum[blockIdx.x] = s;
    }
}

__global__ void scanB_k(const int* __restrict__ bsum, int* __restrict__ boff, int nb) {
    if (gtid() == 0) {
        int s = 0;
        for (int j = 0; j < nb; j++) { boff[j] = s; s += bsum[j]; }
    }
}

__global__ __launch_bounds__(1024) void scanC_k(const int* __restrict__ counts,
                                                const int* __restrict__ boff,
                                                int* __restrict__ row_start,
                                                int* __restrict__ cursor) {
    __shared__ int arr[1024];
    int i = blockIdx.x * 1024 + threadIdx.x;
    int v = (i < NN) ? counts[i] : 0;
    arr[threadIdx.x] = v;
    __syncthreads();
    for (int off = 1; off < 1024; off <<= 1) {
        int t = (threadIdx.x >= (unsigned)off) ? arr[threadIdx.x - off] : 0;
        __syncthreads();
        arr[threadIdx.x] += t;
        __syncthreads();
    }
    if (i < NN) {
        int e = arr[threadIdx.x] - v + boff[blockIdx.x];  // exclusive
        row_start[i] = e;
        cursor[i]    = e;
    }
    if (i == 0) row_start[NN] = NE;
}

__global__ __launch_bounds__(256) void fill_k(const int* __restrict__ srcv,
                                              const int* __restrict__ dstv,
                                              int* __restrict__ cursor,
                                              int* __restrict__ csr_src) {
    for (int i = gtid(); i < NE; i += gridDim.x * blockDim.x) {
        int d   = dstv[i];
        int pos = atomicAdd(&cursor[d], 1);
        csr_src[pos] = srcv[i];
    }
}

// ---------------- dense matmuls (VALU, weights in LDS) ----------------

// out[r][c] = sum_k X[r][k] * W[k][c] (+ bias[c]); W is [128][128] row-major.
// 256 thr: c = tid&127, rg = tid>>7; 16 rows/tile, 8 rows per thread.
template <bool BIAS>
__global__ __launch_bounds__(256) void mm128_k(const float* __restrict__ X,
                                               const float* __restrict__ W,
                                               const float* __restrict__ bias,
                                               float* __restrict__ out) {
    __shared__ float wl[D * D];  // 64 KiB, [k][c]: lanes read consecutive banks
    for (int j = threadIdx.x; j < D * D; j += 256) wl[j] = W[j];
    __syncthreads();
    int c = threadIdx.x & 127, rg = threadIdx.x >> 7;
    float bv = BIAS ? bias[c] : 0.f;
    for (int r0 = blockIdx.x * 16; r0 < NN; r0 += gridDim.x * 16) {  // 100000%16==0
        int rbase = r0 + rg * 8;
        float acc[8] = {};
        for (int k = 0; k < D; k += 4) {
            float4 xv[8];
#pragma unroll
            for (int q = 0; q < 8; q++)
                xv[q] = *(const float4*)&X[(size_t)(rbase + q) * D + k];
#pragma unroll
            for (int kk = 0; kk < 4; kk++) {
                float w = wl[(k + kk) * D + c];
#pragma unroll
                for (int q = 0; q < 8; q++)
                    acc[q] += w * ((const float*)&xv[q])[kk];
            }
        }
#pragma unroll
        for (int q = 0; q < 8; q++)
            out[(size_t)(rbase + q) * D + c] = acc[q] + bv;
    }
}

// Fused: hl = H@W2L, hr = H@W2R + b2. 256 thr: col = tid&31 (0-15 -> L,
// 16-31 -> R), rg = tid>>5; 32 rows/tile, 4 rows per thread.
__global__ __launch_bounds__(256) void mm16_k(const float* __restrict__ H,
                                              const float* __restrict__ W2L,
                                              const float* __restrict__ W2R,
                                              const float* __restrict__ B2,
                                              float* __restrict__ hl,
                                              float* __restrict__ hr) {
    __shared__ float wl[D * 32];  // [k][32]: cols 0-15 = W2L, 16-31 = W2R
    for (int j = threadIdx.x; j < D * NC; j += 256) {
        int r = j >> 4, cc = j & 15;
        wl[r * 32 + cc]      = W2L[j];
        wl[r * 32 + 16 + cc] = W2R[j];
    }
    __syncthreads();
    int col = threadIdx.x & 31, rg = threadIdx.x >> 5;
    float bv = (col >= 16) ? B2[col - 16] : 0.f;
    for (int r0 = blockIdx.x * 32; r0 < NN; r0 += gridDim.x * 32) {  // 100000%32==0
        int rbase = r0 + rg * 4;
        float acc[4] = {};
        for (int k = 0; k < D; k += 4) {
            float4 xv[4];
#pragma unroll
            for (int q = 0; q < 4; q++)
                xv[q] = *(const float4*)&H[(size_t)(rbase + q) * D + k];
#pragma unroll
            for (int kk = 0; kk < 4; kk++) {
                float w = wl[(k + kk) * 32 + col];
#pragma unroll
                for (int q = 0; q < 4; q++)
                    acc[q] += w * ((const float*)&xv[q])[kk];
            }
        }
#pragma unroll
        for (int q = 0; q < 4; q++) {
            int r = rbase + q;
            if (col < 16) hl[(size_t)r * NC + col] = acc[q];
            else          hr[(size_t)r * NC + (col - 16)] = acc[q] + bv;
        }
    }
}

// ---------------- aggregation ----------------

// Wave per node: h[i] = relu(mean_j xl[src_j] + xr[i]); each lane owns 2 feats.
__global__ __launch_bounds__(256) void agg1_k(const float* __restrict__ xl,
                                              const float* __restrict__ xr,
                                              const int* __restrict__ row_start,
                                              const int* __restrict__ csr_src,
                                              float* __restrict__ h) {
    int node = (blockIdx.x * blockDim.x + threadIdx.x) >> 6;
    int lane = threadIdx.x & 63;
    if (node >= NN) return;
    int beg = row_start[node], end = row_start[node + 1];
    const float2* xl2 = (const float2*)xl;
    float ax = 0.f, ay = 0.f;
    int j = beg;
    for (; j + 1 < end; j += 2) {  // 2-deep to break serial idx->gather chain
        int s0 = csr_src[j], s1 = csr_src[j + 1];
        float2 v0 = xl2[(size_t)s0 * 64 + lane];
        float2 v1 = xl2[(size_t)s1 * 64 + lane];
        ax += v0.x + v1.x;
        ay += v0.y + v1.y;
    }
    if (j < end) {
        float2 v = xl2[(size_t)csr_src[j] * 64 + lane];
        ax += v.x; ay += v.y;
    }
    float inv = 1.f / fmaxf((float)(end - beg), 1.f);
    float2 r = ((const float2*)xr)[(size_t)node * 64 + lane];
    float2 o;
    o.x = fmaxf(ax * inv + r.x, 0.f);
    o.y = fmaxf(ay * inv + r.y, 0.f);
    ((float2*)h)[(size_t)node * 64 + lane] = o;
}

// Wave per node: out[i] = log_softmax(mean_j hl[src_j] + hr[i]).
// lane = g*16 + c: 4 edge-groups x 16 classes; shfl-reduce groups then classes.
__global__ __launch_bounds__(256) void agg2_k(const float* __restrict__ hl,
                                              const float* __restrict__ hr,
                                              const int* __restrict__ row_start,
                                              const int* __restrict__ csr_src,
                                              float* __restrict__ out) {
    int node = (blockIdx.x * blockDim.x + threadIdx.x) >> 6;
    int lane = threadIdx.x & 63;
    if (node >= NN) return;
    int c = lane & 15, g = lane >> 4;
    int beg = row_start[node], end = row_start[node + 1];
    float acc = 0.f;
    for (int j = beg + g; j < end; j += 4)
        acc += hl[(size_t)csr_src[j] * NC + c];
    acc += __shfl_xor(acc, 16);
    acc += __shfl_xor(acc, 32);  // all lanes: full edge sum for class c
    float inv = 1.f / fmaxf((float)(end - beg), 1.f);
    float o = acc * inv + hr[(size_t)node * NC + c];
    float m = o;
#pragma unroll
    for (int d = 1; d < 16; d <<= 1) m = fmaxf(m, __shfl_xor(m, d));
    float e = expf(o - m);
    float s = e;
#pragma unroll
    for (int d = 1; d < 16; d <<= 1) s += __shfl_xor(s, d);
    float res = o - m - logf(s);
    if (lane < 16) out[(size_t)node * NC + c] = res;
}

// ---------------- launch ----------------

extern "C" void kernel_launch(void* const* d_in, const int* in_sizes, int n_in,
                              void* d_out, int out_size, void* d_ws, size_t ws_size,
                              hipStream_t stream) {
    const float* x   = (const float*)d_in[0];
    const int*   ei  = (const int*)d_in[1];
    const float* w1l = (const float*)d_in[2];
    const float* w1r = (const float*)d_in[3];
    const float* b1  = (const float*)d_in[4];
    const float* w2l = (const float*)d_in[5];
    const float* w2r = (const float*)d_in[6];
    const float* b2  = (const float*)d_in[7];
    float* out = (float*)d_out;
    const int* srcv = ei;        // edge_index[0]
    const int* dstv = ei + NE;   // edge_index[1]

    // workspace carve-up (~174 MB total)
    char* p = (char*)d_ws;
    auto carve = [&](size_t bytes) -> void* {
        void* r = (void*)p;
        p += (bytes + 255) & ~(size_t)255;
        return r;
    };
    float* xl        = (float*)carve(sizeof(float) * (size_t)NN * D);
    float* xr        = (float*)carve(sizeof(float) * (size_t)NN * D);
    float* h         = (float*)carve(sizeof(float) * (size_t)NN * D);
    float* hl        = (float*)carve(sizeof(float) * (size_t)NN * NC);
    float* hr        = (float*)carve(sizeof(float) * (size_t)NN * NC);
    int*   csr_src   = (int*)carve(sizeof(int) * (size_t)NE);
    int*   counts    = (int*)carve(sizeof(int) * (NN + 32));
    int*   row_start = (int*)carve(sizeof(int) * (NN + 32));
    int*   cursor    = (int*)carve(sizeof(int) * (NN + 32));
    int*   bsum      = (int*)carve(sizeof(int) * 128);
    int*   boff      = (int*)carve(sizeof(int) * 128);

    hipMemsetAsync(counts, 0, sizeof(int) * NN, stream);

    count_k<<<2048, 256, 0, stream>>>(dstv, counts);
    scanA_k<<<98, 1024, 0, stream>>>(counts, bsum);
    scanB_k<<<1, 64, 0, stream>>>(bsum, boff, 98);
    scanC_k<<<98, 1024, 0, stream>>>(counts, boff, row_start, cursor);
    fill_k<<<2048, 256, 0, stream>>>(srcv, dstv, cursor, csr_src);

    mm128_k<false><<<512, 256, 0, stream>>>(x, w1l, nullptr, xl);
    mm128_k<true ><<<512, 256, 0, stream>>>(x, w1r, b1, xr);
    agg1_k<<<25000, 256, 0, stream>>>(xl, xr, row_start, csr_src, h);

    mm16_k<<<512, 256, 0, stream>>>(h, w2l, w2r, b2, hl, hr);
    agg2_k<<<25000, 256, 0, stream>>>(hl, hr, row_start, csr_src, out);
}

// Round 2
// 615.155 us; speedup vs baseline: 1.6012x; 1.6012x over previous
//
#include <hip/hip_runtime.h>

// GraphSAGE 2-layer forward on MI355X.
//  - CSR build (histogram + scan + fill), no f32 atomics anywhere.
//  - Layer 1: fused LDS-tiled VALU GEMM (no fp32 MFMA on CDNA4):
//    xl = x@w1_l, xr = x@w1_r + b1. Tile 128x128, 8x8 register blocking,
//    X tile XOR-swizzled in LDS (row stride 512B would be 4-way bank conflict).
//  - agg1: wave-per-node gather-mean over xl + relu -> h.
//  - Layer 2 transform-first: [hl|hr] = h@[w2_l|w2_r] (LDS-tiled, 64-row tile),
//    then wave-per-node 16-wide gather + fused log_softmax.

#define NN 100000
#define NE 1600000
#define D  128
#define NC 16

__device__ __forceinline__ int gtid() { return blockIdx.x * blockDim.x + threadIdx.x; }

// ---------------- CSR build ----------------

__global__ __launch_bounds__(256) void count_k(const int* __restrict__ dstv,
                                               int* __restrict__ counts) {
    for (int i = gtid(); i < NE; i += gridDim.x * blockDim.x)
        atomicAdd(&counts[dstv[i]], 1);
}

__global__ __launch_bounds__(1024) void scanA_k(const int* __restrict__ counts,
                                                int* __restrict__ bsum) {
    __shared__ int red[16];
    int i = blockIdx.x * 1024 + threadIdx.x;
    int v = (i < NN) ? counts[i] : 0;
#pragma unroll
    for (int o = 32; o > 0; o >>= 1) v += __shfl_down(v, o);
    int w = threadIdx.x >> 6, lane = threadIdx.x & 63;
    if (lane == 0) red[w] = v;
    __syncthreads();
    if (threadIdx.x == 0) {
        int s = 0;
        for (int j = 0; j < 16; j++) s += red[j];
        bsum[blockIdx.x] = s;
    }
}

__global__ void scanB_k(const int* __restrict__ bsum, int* __restrict__ boff, int nb) {
    if (gtid() == 0) {
        int s = 0;
        for (int j = 0; j < nb; j++) { boff[j] = s; s += bsum[j]; }
    }
}

__global__ __launch_bounds__(1024) void scanC_k(const int* __restrict__ counts,
                                                const int* __restrict__ boff,
                                                int* __restrict__ row_start,
                                                int* __restrict__ cursor) {
    __shared__ int arr[1024];
    int i = blockIdx.x * 1024 + threadIdx.x;
    int v = (i < NN) ? counts[i] : 0;
    arr[threadIdx.x] = v;
    __syncthreads();
    for (int off = 1; off < 1024; off <<= 1) {
        int t = (threadIdx.x >= (unsigned)off) ? arr[threadIdx.x - off] : 0;
        __syncthreads();
        arr[threadIdx.x] += t;
        __syncthreads();
    }
    if (i < NN) {
        int e = arr[threadIdx.x] - v + boff[blockIdx.x];  // exclusive
        row_start[i] = e;
        cursor[i]    = e;
    }
    if (i == 0) row_start[NN] = NE;
}

__global__ __launch_bounds__(256) void fill_k(const int* __restrict__ srcv,
                                              const int* __restrict__ dstv,
                                              int* __restrict__ cursor,
                                              int* __restrict__ csr_src) {
    for (int i = gtid(); i < NE; i += gridDim.x * blockDim.x) {
        int d   = dstv[i];
        int pos = atomicAdd(&cursor[d], 1);
        csr_src[pos] = srcv[i];
    }
}

// ---------------- layer-1 GEMM: 128x128 tile, LDS-staged, 8x8 reg blocking ---

// grid (782, 2): y=0 -> out=xl (W1L, no bias), y=1 -> out=xr (W1R + b1).
// block 256 = tx(0..15) x ty(0..15). Thread computes rows {ty*4+i, 64+ty*4+i}
// (i<4) x cols {tx*4+j, 64+tx*4+j} (j<4).
// X tile in LDS as float4[r][kb ^ ((r>>2)&3)] — swizzle makes the 4 distinct
// row-addresses of a wave's b128 read land in different bank quads.
// W tile linear float4[k][cb]; reads are 2-way bank aliased (free).

#define MM_LOAD(XA, WB, ks)                                              \
    {                                                                    \
        int kx_ = (ks) ^ (ty & 3);                                       \
        _Pragma("unroll") for (int i_ = 0; i_ < 4; ++i_) {               \
            XA[i_]     = xs[(ty * 4 + i_) * 32 + kx_];                   \
            XA[4 + i_] = xs[(64 + ty * 4 + i_) * 32 + kx_];              \
        }                                                                \
        _Pragma("unroll") for (int kk_ = 0; kk_ < 4; ++kk_) {            \
            WB[kk_][0] = ws[((ks) * 4 + kk_) * 32 + tx];                 \
            WB[kk_][1] = ws[((ks) * 4 + kk_) * 32 + 16 + tx];            \
        }                                                                \
    }

#define MM_FMA(XA, WB)                                                   \
    _Pragma("unroll") for (int kk_ = 0; kk_ < 4; ++kk_)                  \
    _Pragma("unroll") for (int i_ = 0; i_ < 8; ++i_) {                   \
        float xv_ = ((const float*)&XA[i_])[kk_];                        \
        _Pragma("unroll") for (int j_ = 0; j_ < 4; ++j_) {               \
            acc[i_][j_]     += xv_ * ((const float*)&WB[kk_][0])[j_];    \
            acc[i_][4 + j_] += xv_ * ((const float*)&WB[kk_][1])[j_];    \
        }                                                                \
    }

__global__ __launch_bounds__(256, 1) void mmL1_k(const float* __restrict__ X,
                                                 const float* __restrict__ WL,
                                                 const float* __restrict__ WR,
                                                 const float* __restrict__ b1,
                                                 float* __restrict__ outL,
                                                 float* __restrict__ outR) {
    __shared__ float4 xs[128 * 32];  // 64 KiB
    __shared__ float4 ws[128 * 32];  // 64 KiB
    const int tid = threadIdx.x;
    const int tx = tid & 15, ty = tid >> 4;
    const int r0 = blockIdx.x * 128;
    const float* __restrict__ W = blockIdx.y ? WR : WL;
    float* __restrict__ out = blockIdx.y ? outR : outL;

    // stage: X swizzled (reg-staged), W linear. 16 float4 each per thread.
    const float4* X4 = (const float4*)X;
    const float4* W4 = (const float4*)W;
#pragma unroll
    for (int it = 0; it < 16; ++it) {
        int v  = tid + it * 256;          // float4 index 0..4095
        int r  = v >> 5, kb = v & 31;
        int gr = r0 + r; if (gr >= NN) gr = NN - 1;  // clamp (stores guarded)
        xs[r * 32 + (kb ^ ((r >> 2) & 3))] = X4[(size_t)gr * 32 + kb];
        ws[v] = W4[v];
    }
    __syncthreads();

    float acc[8][8] = {};
    float4 xa0[8], xa1[8], wb0[4][2], wb1[4][2];

    MM_LOAD(xa0, wb0, 0);
#pragma unroll 1
    for (int ks = 0; ks < 30; ks += 2) {
        MM_LOAD(xa1, wb1, ks + 1);
        MM_FMA(xa0, wb0);
        MM_LOAD(xa0, wb0, ks + 2);
        MM_FMA(xa1, wb1);
    }
    MM_LOAD(xa1, wb1, 31);
    MM_FMA(xa0, wb0);
    MM_FMA(xa1, wb1);

    // epilogue
    float bv[8];
#pragma unroll
    for (int j = 0; j < 4; ++j) {
        bv[j]     = blockIdx.y ? b1[tx * 4 + j] : 0.f;
        bv[4 + j] = blockIdx.y ? b1[64 + tx * 4 + j] : 0.f;
    }
#pragma unroll
    for (int i = 0; i < 8; ++i) {
        int r  = (i < 4) ? (ty * 4 + i) : (64 + ty * 4 + (i - 4));
        int gr = r0 + r;
        if (gr < NN) {
            float4 o0, o1;
            o0.x = acc[i][0] + bv[0]; o0.y = acc[i][1] + bv[1];
            o0.z = acc[i][2] + bv[2]; o0.w = acc[i][3] + bv[3];
            o1.x = acc[i][4] + bv[4]; o1.y = acc[i][5] + bv[5];
            o1.z = acc[i][6] + bv[6]; o1.w = acc[i][7] + bv[7];
            ((float4*)out)[(size_t)gr * 32 + tx]      = o0;
            ((float4*)out)[(size_t)gr * 32 + 16 + tx] = o1;
        }
    }
}

// ---------------- layer-2 GEMM: 64-row tile, fused [W2L|W2R] ----------------

// block 256 = tx(0..15) x ty(0..15); thread: rows ty*4+i (i<4), col pair
// {tx*2, tx*2+1} where tx<8 -> W2L cols, tx>=8 -> W2R cols. 48 KiB LDS.
__global__ __launch_bounds__(256) void mm16_k(const float* __restrict__ H,
                                              const float* __restrict__ W2L,
                                              const float* __restrict__ W2R,
                                              const float* __restrict__ B2,
                                              float* __restrict__ hl,
                                              float* __restrict__ hr) {
    __shared__ float4 xs[64 * 32];    // 32 KiB, swizzled like mmL1
    __shared__ float2 ws[128 * 16];   // 16 KiB: [k][cc2] cc2<8 = L, >=8 = R
    const int tid = threadIdx.x;
    const int tx = tid & 15, ty = tid >> 4;
    const int r0 = blockIdx.x * 64;

    const float4* H4 = (const float4*)H;
#pragma unroll
    for (int it = 0; it < 8; ++it) {
        int v  = tid + it * 256;          // 0..2047
        int r  = v >> 5, kb = v & 31;
        int gr = r0 + r; if (gr >= NN) gr = NN - 1;
        xs[r * 32 + (kb ^ ((r >> 2) & 3))] = H4[(size_t)gr * 32 + kb];
    }
    const float2* L2 = (const float2*)W2L;
    const float2* R2 = (const float2*)W2R;
#pragma unroll
    for (int it = 0; it < 4; ++it) {
        int v = tid + it * 256;           // float2 index 0..1023
        int k = v >> 3, cc2 = v & 7;
        ws[k * 16 + cc2]     = L2[v];
        ws[k * 16 + 8 + cc2] = R2[v];
    }
    __syncthreads();

    float acc[4][2] = {};
#pragma unroll 1
    for (int ks = 0; ks < 32; ++ks) {
        float4 xa[4];
        float2 wb[4];
        int kx = ks ^ (ty & 3);
#pragma unroll
        for (int i = 0; i < 4; ++i) xa[i] = xs[(ty * 4 + i) * 32 + kx];
#pragma unroll
        for (int kk = 0; kk < 4; ++kk) wb[kk] = ws[(ks * 4 + kk) * 16 + tx];
#pragma unroll
        for (int kk = 0; kk < 4; ++kk)
#pragma unroll
            for (int i = 0; i < 4; ++i) {
                float xv = ((const float*)&xa[i])[kk];
                acc[i][0] += xv * wb[kk].x;
                acc[i][1] += xv * wb[kk].y;
            }
    }

#pragma unroll
    for (int i = 0; i < 4; ++i) {
        int gr = r0 + ty * 4 + i;
        if (gr >= NN) continue;
        if (tx < 8) {
            hl[(size_t)gr * NC + tx * 2]     = acc[i][0];
            hl[(size_t)gr * NC + tx * 2 + 1] = acc[i][1];
        } else {
            int c = (tx - 8) * 2;
            hr[(size_t)gr * NC + c]     = acc[i][0] + B2[c];
            hr[(size_t)gr * NC + c + 1] = acc[i][1] + B2[c + 1];
        }
    }
}

// ---------------- aggregation ----------------

__global__ __launch_bounds__(256) void agg1_k(const float* __restrict__ xl,
                                              const float* __restrict__ xr,
                                              const int* __restrict__ row_start,
                                              const int* __restrict__ csr_src,
                                              float* __restrict__ h) {
    int node = (blockIdx.x * blockDim.x + threadIdx.x) >> 6;
    int lane = threadIdx.x & 63;
    if (node >= NN) return;
    int beg = row_start[node], end = row_start[node + 1];
    const float2* xl2 = (const float2*)xl;
    float ax = 0.f, ay = 0.f;
    int j = beg;
    for (; j + 1 < end; j += 2) {
        int s0 = csr_src[j], s1 = csr_src[j + 1];
        float2 v0 = xl2[(size_t)s0 * 64 + lane];
        float2 v1 = xl2[(size_t)s1 * 64 + lane];
        ax += v0.x + v1.x;
        ay += v0.y + v1.y;
    }
    if (j < end) {
        float2 v = xl2[(size_t)csr_src[j] * 64 + lane];
        ax += v.x; ay += v.y;
    }
    float inv = 1.f / fmaxf((float)(end - beg), 1.f);
    float2 r = ((const float2*)xr)[(size_t)node * 64 + lane];
    float2 o;
    o.x = fmaxf(ax * inv + r.x, 0.f);
    o.y = fmaxf(ay * inv + r.y, 0.f);
    ((float2*)h)[(size_t)node * 64 + lane] = o;
}

__global__ __launch_bounds__(256) void agg2_k(const float* __restrict__ hl,
                                              const float* __restrict__ hr,
                                              const int* __restrict__ row_start,
                                              const int* __restrict__ csr_src,
                                              float* __restrict__ out) {
    int node = (blockIdx.x * blockDim.x + threadIdx.x) >> 6;
    int lane = threadIdx.x & 63;
    if (node >= NN) return;
    int c = lane & 15, g = lane >> 4;
    int beg = row_start[node], end = row_start[node + 1];
    float acc = 0.f;
    for (int j = beg + g; j < end; j += 4)
        acc += hl[(size_t)csr_src[j] * NC + c];
    acc += __shfl_xor(acc, 16);
    acc += __shfl_xor(acc, 32);
    float inv = 1.f / fmaxf((float)(end - beg), 1.f);
    float o = acc * inv + hr[(size_t)node * NC + c];
    float m = o;
#pragma unroll
    for (int d = 1; d < 16; d <<= 1) m = fmaxf(m, __shfl_xor(m, d));
    float e = expf(o - m);
    float s = e;
#pragma unroll
    for (int d = 1; d < 16; d <<= 1) s += __shfl_xor(s, d);
    float res = o - m - logf(s);
    if (lane < 16) out[(size_t)node * NC + c] = res;
}

// ---------------- launch ----------------

extern "C" void kernel_launch(void* const* d_in, const int* in_sizes, int n_in,
                              void* d_out, int out_size, void* d_ws, size_t ws_size,
                              hipStream_t stream) {
    const float* x   = (const float*)d_in[0];
    const int*   ei  = (const int*)d_in[1];
    const float* w1l = (const float*)d_in[2];
    const float* w1r = (const float*)d_in[3];
    const float* b1  = (const float*)d_in[4];
    const float* w2l = (const float*)d_in[5];
    const float* w2r = (const float*)d_in[6];
    const float* b2  = (const float*)d_in[7];
    float* out = (float*)d_out;
    const int* srcv = ei;        // edge_index[0]
    const int* dstv = ei + NE;   // edge_index[1]

    char* p = (char*)d_ws;
    auto carve = [&](size_t bytes) -> void* {
        void* r = (void*)p;
        p += (bytes + 255) & ~(size_t)255;
        return r;
    };
    float* xl        = (float*)carve(sizeof(float) * (size_t)NN * D);
    float* xr        = (float*)carve(sizeof(float) * (size_t)NN * D);
    float* h         = (float*)carve(sizeof(float) * (size_t)NN * D);
    float* hl        = (float*)carve(sizeof(float) * (size_t)NN * NC);
    float* hr        = (float*)carve(sizeof(float) * (size_t)NN * NC);
    int*   csr_src   = (int*)carve(sizeof(int) * (size_t)NE);
    int*   counts    = (int*)carve(sizeof(int) * (NN + 32));
    int*   row_start = (int*)carve(sizeof(int) * (NN + 32));
    int*   cursor    = (int*)carve(sizeof(int) * (NN + 32));
    int*   bsum      = (int*)carve(sizeof(int) * 128);
    int*   boff      = (int*)carve(sizeof(int) * 128);

    hipMemsetAsync(counts, 0, sizeof(int) * NN, stream);

    count_k<<<2048, 256, 0, stream>>>(dstv, counts);
    scanA_k<<<98, 1024, 0, stream>>>(counts, bsum);
    scanB_k<<<1, 64, 0, stream>>>(bsum, boff, 98);
    scanC_k<<<98, 1024, 0, stream>>>(counts, boff, row_start, cursor);
    fill_k<<<2048, 256, 0, stream>>>(srcv, dstv, cursor, csr_src);

    mmL1_k<<<dim3(782, 2), 256, 0, stream>>>(x, w1l, w1r, b1, xl, xr);
    agg1_k<<<25000, 256, 0, stream>>>(xl, xr, row_start, csr_src, h);

    mm16_k<<<1563, 256, 0, stream>>>(h, w2l, w2r, b2, hl, hr);
    agg2_k<<<25000, 256, 0, stream>>>(hl, hr, row_start, csr_src, out);
}

// Round 3
// 545.914 us; speedup vs baseline: 1.8043x; 1.1268x over previous
//
#include <hip/hip_runtime.h>

// GraphSAGE 2-layer forward on MI355X.
//  - CSR build (histogram + scan + fill), no f32 atomics anywhere.
//  - Layer 1: split-bf16 MFMA GEMM (x=hi+lo, W=hi+lo; 3 MFMA terms, f32 acc
//    ~= f32 GEMM to ~1e-4 rel). xl = x@w1_l, xr = x@w1_r + b1 in ONE block
//    pass pair (X staged once). W pre-transposed/split/swizzled by prep kernel.
//  - agg1: wave-per-node gather-mean over xl + relu -> h (4-deep ILP).
//  - Layer 2 transform-first: [hl|hr] = h@[w2_l|w2_r] (VALU, small), then
//    wave-per-node 16-wide gather + fused log_softmax.

#define NN 100000
#define NE 1600000
#define D  128
#define NC 16

typedef unsigned short ushort;
typedef __bf16 bf16x8 __attribute__((ext_vector_type(8)));
typedef __bf16 bf16x4 __attribute__((ext_vector_type(4)));
typedef float  f32x4  __attribute__((ext_vector_type(4)));

#define AS1(p) ((const __attribute__((address_space(1))) void*)(p))
#define AS3(p) ((__attribute__((address_space(3))) void*)(p))

__device__ __forceinline__ int gtid() { return blockIdx.x * blockDim.x + threadIdx.x; }

// ---------------- CSR build ----------------

__global__ __launch_bounds__(256) void count_k(const int* __restrict__ dstv,
                                               int* __restrict__ counts) {
    for (int i = gtid(); i < NE; i += gridDim.x * blockDim.x)
        atomicAdd(&counts[dstv[i]], 1);
}

__global__ __launch_bounds__(1024) void scanA_k(const int* __restrict__ counts,
                                                int* __restrict__ bsum) {
    __shared__ int red[16];
    int i = blockIdx.x * 1024 + threadIdx.x;
    int v = (i < NN) ? counts[i] : 0;
#pragma unroll
    for (int o = 32; o > 0; o >>= 1) v += __shfl_down(v, o);
    int w = threadIdx.x >> 6, lane = threadIdx.x & 63;
    if (lane == 0) red[w] = v;
    __syncthreads();
    if (threadIdx.x == 0) {
        int s = 0;
        for (int j = 0; j < 16; j++) s += red[j];
        bsum[blockIdx.x] = s;
    }
}

__global__ void scanB_k(const int* __restrict__ bsum, int* __restrict__ boff, int nb) {
    if (gtid() == 0) {
        int s = 0;
        for (int j = 0; j < nb; j++) { boff[j] = s; s += bsum[j]; }
    }
}

__global__ __launch_bounds__(1024) void scanC_k(const int* __restrict__ counts,
                                                const int* __restrict__ boff,
                                                int* __restrict__ row_start,
                                                int* __restrict__ cursor) {
    __shared__ int arr[1024];
    int i = blockIdx.x * 1024 + threadIdx.x;
    int v = (i < NN) ? counts[i] : 0;
    arr[threadIdx.x] = v;
    __syncthreads();
    for (int off = 1; off < 1024; off <<= 1) {
        int t = (threadIdx.x >= (unsigned)off) ? arr[threadIdx.x - off] : 0;
        __syncthreads();
        arr[threadIdx.x] += t;
        __syncthreads();
    }
    if (i < NN) {
        int e = arr[threadIdx.x] - v + boff[blockIdx.x];  // exclusive
        row_start[i] = e;
        cursor[i]    = e;
    }
    if (i == 0) row_start[NN] = NE;
}

__global__ __launch_bounds__(256) void fill_k(const int* __restrict__ srcv,
                                              const int* __restrict__ dstv,
                                              int* __restrict__ cursor,
                                              int* __restrict__ csr_src) {
    for (int i = gtid(); i < NE; i += gridDim.x * blockDim.x) {
        int d   = dstv[i];
        int pos = atomicAdd(&cursor[d], 1);
        csr_src[pos] = srcv[i];
    }
}

// ---------------- W prep: transpose + bf16 split + swizzle ----------------

// wt layout (64 KiB per matrix): bytes [0,32K) hi, [32K,64K) lo.
// Element (k, c) at byte c*256 + ((k*2) ^ ((c&7)<<4)) — matches mmL1 LDS reads.
__global__ __launch_bounds__(256) void prepw_k(const float* __restrict__ WL,
                                               const float* __restrict__ WR,
                                               ushort* __restrict__ wtL,
                                               ushort* __restrict__ wtR) {
    int t = gtid();
    if (t >= 2 * D * D) return;
    const float* W  = (t < D * D) ? WL : WR;
    ushort*      wt = (t < D * D) ? wtL : wtR;
    int e = t & (D * D - 1);
    int k = e >> 7, c = e & 127;          // e = k*128 + c (row-major [k][c])
    float w = W[e];
    __bf16 hi = (__bf16)w;
    __bf16 lo = (__bf16)(w - (float)hi);
    int byte = c * 256 + ((k * 2) ^ ((c & 7) << 4));
    *(ushort*)((char*)wt + byte)         = __builtin_bit_cast(ushort, hi);
    *(ushort*)((char*)wt + 32768 + byte) = __builtin_bit_cast(ushort, lo);
}

// ---------------- layer-1 GEMM: split-bf16 MFMA ----------------

// 512 thr = 8 waves; BM=128 rows (wave w: rows w*16..+15), BN=128, K=128 whole.
// LDS 128 KiB: xh 32K | xlo 32K | w(hi+lo) 64K. XOR swizzle byte^=((row&7)<<4).
__global__ __launch_bounds__(512, 1) void mmL1_k(const float* __restrict__ X,
                                                 const ushort* __restrict__ wtL,
                                                 const ushort* __restrict__ wtR,
                                                 const float* __restrict__ b1,
                                                 float* __restrict__ outL,
                                                 float* __restrict__ outR) {
    __shared__ ushort s_xh[128 * 128];   // 32 KiB
    __shared__ ushort s_xl[128 * 128];   // 32 KiB
    __shared__ ushort s_w[2 * 128 * 128];// 64 KiB (hi | lo)
    const int tid = threadIdx.x;
    const int wv = tid >> 6, ln = tid & 63;
    const int lr = ln & 15, lg = ln >> 4;
    const int r0 = blockIdx.x * 128;

    // ---- stage X: f32 -> bf16 hi/lo, swizzled ds_write (once) ----
    const float4* X4 = (const float4*)X;
#pragma unroll
    for (int it = 0; it < 8; ++it) {
        int v  = it * 512 + tid;          // 0..4095 float4s
        int r  = v >> 5, kq = v & 31;
        int gr = r0 + r; if (gr >= NN) gr = NN - 1;   // clamp; stores guarded
        float4 xv = X4[(size_t)gr * 32 + kq];
        bf16x4 hi, lo;
#pragma unroll
        for (int j = 0; j < 4; ++j) {
            float f = ((const float*)&xv)[j];
            __bf16 h = (__bf16)f;
            hi[j] = h;
            lo[j] = (__bf16)(f - (float)h);
        }
        int byte = r * 256 + ((kq * 8) ^ ((r & 7) << 4));
        *(bf16x4*)((char*)s_xh + byte) = hi;
        *(bf16x4*)((char*)s_xl + byte) = lo;
    }

    const int swzA = (((wv * 16 + lr) & 7) << 4);
    const int rowA = wv * 16 + lr;
    const int swzB = ((lr & 7) << 4);

#pragma unroll 1
    for (int pass = 0; pass < 2; ++pass) {
        // ---- stage W (64 KiB linear copy; source is pre-swizzled) ----
        const char* wsrc = (const char*)(pass ? wtR : wtL) + ln * 16;
#pragma unroll
        for (int c2 = 0; c2 < 8; ++c2) {
            int chunk = wv * 8 + c2;
            __builtin_amdgcn_global_load_lds(AS1(wsrc + chunk * 1024),
                                             AS3((char*)s_w + chunk * 1024),
                                             16, 0, 0);
        }
        __syncthreads();   // drains vmcnt (gload_lds) + lgkm (ds_writes)

        f32x4 acc[8];
#pragma unroll
        for (int nt = 0; nt < 8; ++nt) acc[nt] = f32x4{0.f, 0.f, 0.f, 0.f};

#pragma unroll
        for (int ks = 0; ks < 4; ++ks) {
            int kb = ks * 64 + lg * 16;
            int offA = rowA * 256 + (kb ^ swzA);
            bf16x8 ah = *(const bf16x8*)((const char*)s_xh + offA);
            bf16x8 al = *(const bf16x8*)((const char*)s_xl + offA);
#pragma unroll
            for (int nt = 0; nt < 8; ++nt) {
                int offB = (nt * 16 + lr) * 256 + (kb ^ swzB);
                bf16x8 bh = *(const bf16x8*)((const char*)s_w + offB);
                bf16x8 bl = *(const bf16x8*)((const char*)s_w + 32768 + offB);
                acc[nt] = __builtin_amdgcn_mfma_f32_16x16x32_bf16(ah, bh, acc[nt], 0, 0, 0);
                acc[nt] = __builtin_amdgcn_mfma_f32_16x16x32_bf16(ah, bl, acc[nt], 0, 0, 0);
                acc[nt] = __builtin_amdgcn_mfma_f32_16x16x32_bf16(al, bh, acc[nt], 0, 0, 0);
            }
        }

        // ---- epilogue: C/D layout col=lane&15, row=(lane>>4)*4+reg ----
        float* outp = pass ? outR : outL;
        float bb[8];
#pragma unroll
        for (int nt = 0; nt < 8; ++nt) bb[nt] = pass ? b1[nt * 16 + lr] : 0.f;
#pragma unroll
        for (int j = 0; j < 4; ++j) {
            int gr = r0 + wv * 16 + lg * 4 + j;
            if (gr < NN) {
#pragma unroll
                for (int nt = 0; nt < 8; ++nt)
                    outp[(size_t)gr * D + nt * 16 + lr] = acc[nt][j] + bb[nt];
            }
        }
        __syncthreads();   // all waves done reading s_w before restage
    }
}

// ---------------- layer-2 GEMM: 64-row tile, fused [W2L|W2R] ----------------

__global__ __launch_bounds__(256) void mm16_k(const float* __restrict__ H,
                                              const float* __restrict__ W2L,
                                              const float* __restrict__ W2R,
                                              const float* __restrict__ B2,
                                              float* __restrict__ hl,
                                              float* __restrict__ hr) {
    __shared__ float4 xs[64 * 32];    // 32 KiB, swizzled
    __shared__ float2 ws[128 * 16];   // 16 KiB: [k][cc2] cc2<8 = L, >=8 = R
    const int tid = threadIdx.x;
    const int tx = tid & 15, ty = tid >> 4;
    const int r0 = blockIdx.x * 64;

    const float4* H4 = (const float4*)H;
#pragma unroll
    for (int it = 0; it < 8; ++it) {
        int v  = tid + it * 256;          // 0..2047
        int r  = v >> 5, kb = v & 31;
        int gr = r0 + r; if (gr >= NN) gr = NN - 1;
        xs[r * 32 + (kb ^ ((r >> 2) & 3))] = H4[(size_t)gr * 32 + kb];
    }
    const float2* L2 = (const float2*)W2L;
    const float2* R2 = (const float2*)W2R;
#pragma unroll
    for (int it = 0; it < 4; ++it) {
        int v = tid + it * 256;           // float2 index 0..1023
        int k = v >> 3, cc2 = v & 7;
        ws[k * 16 + cc2]     = L2[v];
        ws[k * 16 + 8 + cc2] = R2[v];
    }
    __syncthreads();

    float acc[4][2] = {};
#pragma unroll 1
    for (int ks = 0; ks < 32; ++ks) {
        float4 xa[4];
        float2 wb[4];
        int kx = ks ^ (ty & 3);
#pragma unroll
        for (int i = 0; i < 4; ++i) xa[i] = xs[(ty * 4 + i) * 32 + kx];
#pragma unroll
        for (int kk = 0; kk < 4; ++kk) wb[kk] = ws[(ks * 4 + kk) * 16 + tx];
#pragma unroll
        for (int kk = 0; kk < 4; ++kk)
#pragma unroll
            for (int i = 0; i < 4; ++i) {
                float xv = ((const float*)&xa[i])[kk];
                acc[i][0] += xv * wb[kk].x;
                acc[i][1] += xv * wb[kk].y;
            }
    }

#pragma unroll
    for (int i = 0; i < 4; ++i) {
        int gr = r0 + ty * 4 + i;
        if (gr >= NN) continue;
        if (tx < 8) {
            hl[(size_t)gr * NC + tx * 2]     = acc[i][0];
            hl[(size_t)gr * NC + tx * 2 + 1] = acc[i][1];
        } else {
            int c = (tx - 8) * 2;
            hr[(size_t)gr * NC + c]     = acc[i][0] + B2[c];
            hr[(size_t)gr * NC + c + 1] = acc[i][1] + B2[c + 1];
        }
    }
}

// ---------------- aggregation ----------------

__global__ __launch_bounds__(256) void agg1_k(const float* __restrict__ xl,
                                              const float* __restrict__ xr,
                                              const int* __restrict__ row_start,
                                              const int* __restrict__ csr_src,
                                              float* __restrict__ h) {
    int node = (blockIdx.x * blockDim.x + threadIdx.x) >> 6;
    int lane = threadIdx.x & 63;
    if (node >= NN) return;
    int beg = row_start[node], end = row_start[node + 1];
    const float2* xl2 = (const float2*)xl;
    float ax0 = 0.f, ay0 = 0.f, ax1 = 0.f, ay1 = 0.f;
    float ax2 = 0.f, ay2 = 0.f, ax3 = 0.f, ay3 = 0.f;
    int j = beg;
    for (; j + 3 < end; j += 4) {   // 4 independent gathers in flight
        int s0 = csr_src[j], s1 = csr_src[j + 1];
        int s2 = csr_src[j + 2], s3 = csr_src[j + 3];
        float2 v0 = xl2[(size_t)s0 * 64 + lane];
        float2 v1 = xl2[(size_t)s1 * 64 + lane];
        float2 v2 = xl2[(size_t)s2 * 64 + lane];
        float2 v3 = xl2[(size_t)s3 * 64 + lane];
        ax0 += v0.x; ay0 += v0.y; ax1 += v1.x; ay1 += v1.y;
        ax2 += v2.x; ay2 += v2.y; ax3 += v3.x; ay3 += v3.y;
    }
    for (; j < end; ++j) {
        float2 v = xl2[(size_t)csr_src[j] * 64 + lane];
        ax0 += v.x; ay0 += v.y;
    }
    float ax = (ax0 + ax1) + (ax2 + ax3);
    float ay = (ay0 + ay1) + (ay2 + ay3);
    float inv = 1.f / fmaxf((float)(end - beg), 1.f);
    float2 r = ((const float2*)xr)[(size_t)node * 64 + lane];
    float2 o;
    o.x = fmaxf(ax * inv + r.x, 0.f);
    o.y = fmaxf(ay * inv + r.y, 0.f);
    ((float2*)h)[(size_t)node * 64 + lane] = o;
}

__global__ __launch_bounds__(256) void agg2_k(const float* __restrict__ hl,
                                              const float* __restrict__ hr,
                                              const int* __restrict__ row_start,
                                              const int* __restrict__ csr_src,
                                              float* __restrict__ out) {
    int node = (blockIdx.x * blockDim.x + threadIdx.x) >> 6;
    int lane = threadIdx.x & 63;
    if (node >= NN) return;
    int c = lane & 15, g = lane >> 4;
    int beg = row_start[node], end = row_start[node + 1];
    float acc = 0.f;
    for (int j = beg + g; j < end; j += 4)
        acc += hl[(size_t)csr_src[j] * NC + c];
    acc += __shfl_xor(acc, 16);
    acc += __shfl_xor(acc, 32);
    float inv = 1.f / fmaxf((float)(end - beg), 1.f);
    float o = acc * inv + hr[(size_t)node * NC + c];
    float m = o;
#pragma unroll
    for (int d = 1; d < 16; d <<= 1) m = fmaxf(m, __shfl_xor(m, d));
    float e = expf(o - m);
    float s = e;
#pragma unroll
    for (int d = 1; d < 16; d <<= 1) s += __shfl_xor(s, d);
    float res = o - m - logf(s);
    if (lane < 16) out[(size_t)node * NC + c] = res;
}

// ---------------- launch ----------------

extern "C" void kernel_launch(void* const* d_in, const int* in_sizes, int n_in,
                              void* d_out, int out_size, void* d_ws, size_t ws_size,
                              hipStream_t stream) {
    const float* x   = (const float*)d_in[0];
    const int*   ei  = (const int*)d_in[1];
    const float* w1l = (const float*)d_in[2];
    const float* w1r = (const float*)d_in[3];
    const float* b1  = (const float*)d_in[4];
    const float* w2l = (const float*)d_in[5];
    const float* w2r = (const float*)d_in[6];
    const float* b2  = (const float*)d_in[7];
    float* out = (float*)d_out;
    const int* srcv = ei;        // edge_index[0]
    const int* dstv = ei + NE;   // edge_index[1]

    char* p = (char*)d_ws;
    auto carve = [&](size_t bytes) -> void* {
        void* r = (void*)p;
        p += (bytes + 255) & ~(size_t)255;
        return r;
    };
    float*  xl        = (float*)carve(sizeof(float) * (size_t)NN * D);
    float*  xr        = (float*)carve(sizeof(float) * (size_t)NN * D);
    float*  h         = (float*)carve(sizeof(float) * (size_t)NN * D);
    float*  hl        = (float*)carve(sizeof(float) * (size_t)NN * NC);
    float*  hr        = (float*)carve(sizeof(float) * (size_t)NN * NC);
    int*    csr_src   = (int*)carve(sizeof(int) * (size_t)NE);
    int*    counts    = (int*)carve(sizeof(int) * (NN + 32));
    int*    row_start = (int*)carve(sizeof(int) * (NN + 32));
    int*    cursor    = (int*)carve(sizeof(int) * (NN + 32));
    int*    bsum      = (int*)carve(sizeof(int) * 128);
    int*    boff      = (int*)carve(sizeof(int) * 128);
    ushort* wtL       = (ushort*)carve(sizeof(ushort) * 2 * D * D);
    ushort* wtR       = (ushort*)carve(sizeof(ushort) * 2 * D * D);

    hipMemsetAsync(counts, 0, sizeof(int) * NN, stream);

    count_k<<<2048, 256, 0, stream>>>(dstv, counts);
    scanA_k<<<98, 1024, 0, stream>>>(counts, bsum);
    scanB_k<<<1, 64, 0, stream>>>(bsum, boff, 98);
    scanC_k<<<98, 1024, 0, stream>>>(counts, boff, row_start, cursor);
    fill_k<<<2048, 256, 0, stream>>>(srcv, dstv, cursor, csr_src);

    prepw_k<<<128, 256, 0, stream>>>(w1l, w1r, wtL, wtR);
    mmL1_k<<<782, 512, 0, stream>>>(x, wtL, wtR, b1, xl, xr);
    agg1_k<<<25000, 256, 0, stream>>>(xl, xr, row_start, csr_src, h);

    mm16_k<<<1563, 256, 0, stream>>>(h, w2l, w2r, b2, hl, hr);
    agg2_k<<<25000, 256, 0, stream>>>(hl, hr, row_start, csr_src, out);
}

// Round 6
// 413.298 us; speedup vs baseline: 2.3832x; 1.3209x over previous
//
#include <hip/hip_runtime.h>

// GraphSAGE 2-layer forward on MI355X.
//  - CSR build via 2-level counting sort (NO per-edge scattered 4B writes:
//    round-3 rocprof showed 17x write-amplification = 107MB for 6.4MB array).
//    bucket = dst>>8 (391 buckets x 256 nodes): hist -> scan -> locality-aware
//    partition (packed (dstLow<<17|src)) -> per-bucket LDS counting-sort fill
//    which also emits row_start directly (replaces count_k + 3 scan kernels).
//  - Layer 1: split-bf16 MFMA GEMM (x=hi+lo, W=hi+lo; 3 MFMA terms, f32 acc).
//  - agg1: wave-per-node gather-mean + relu (4-deep ILP).
//  - Layer 2 transform-first (VALU, 16-wide), wave-per-node gather +
//    fused log_softmax.
// (Round 5 resubmission: rounds 4 and 5 benches never ran — GPUAcquisitionTimeout.)

#define NN 100000
#define NE 1600000
#define D  128
#define NC 16

#define BSH 8                 // bucket shift: 256 nodes / bucket
#define NB  391               // ceil(NN / 256)
#define EBLK 8192             // edges per partition block

typedef unsigned short ushort;
typedef __bf16 bf16x8 __attribute__((ext_vector_type(8)));
typedef __bf16 bf16x4 __attribute__((ext_vector_type(4)));
typedef float  f32x4  __attribute__((ext_vector_type(4)));

#define AS1(p) ((const __attribute__((address_space(1))) void*)(p))
#define AS3(p) ((__attribute__((address_space(3))) void*)(p))

__device__ __forceinline__ int gtid() { return blockIdx.x * blockDim.x + threadIdx.x; }

// ---------------- CSR build: 2-level counting sort ----------------

__global__ __launch_bounds__(256) void hist_k(const int* __restrict__ dstv,
                                              int* __restrict__ bucket_cnt) {
    __shared__ int h[NB];
    for (int i = threadIdx.x; i < NB; i += 256) h[i] = 0;
    __syncthreads();
    for (int i = gtid(); i < NE; i += gridDim.x * blockDim.x)
        atomicAdd(&h[dstv[i] >> BSH], 1);
    __syncthreads();
    for (int i = threadIdx.x; i < NB; i += 256)
        if (h[i]) atomicAdd(&bucket_cnt[i], h[i]);
}

__global__ __launch_bounds__(512) void scanb_k(const int* __restrict__ bucket_cnt,
                                               int* __restrict__ bucket_base,
                                               int* __restrict__ bucket_cursor) {
    __shared__ int arr[512];
    int t = threadIdx.x;
    int v = (t < NB) ? bucket_cnt[t] : 0;
    arr[t] = v;
    __syncthreads();
    for (int off = 1; off < 512; off <<= 1) {
        int u = (t >= off) ? arr[t - off] : 0;
        __syncthreads();
        arr[t] += u;
        __syncthreads();
    }
    if (t < NB) {
        int e = arr[t] - v;        // exclusive
        bucket_base[t]   = e;
        bucket_cursor[t] = e;
    }
    if (t == 0) bucket_base[NB] = NE;
}

// Partition edges by bucket; write one packed int per edge. Within a block
// each bucket's positions are consecutive -> write streams are sequential.
__global__ __launch_bounds__(256) void part_k(const int* __restrict__ srcv,
                                              const int* __restrict__ dstv,
                                              int* __restrict__ bucket_cursor,
                                              int* __restrict__ ppack) {
    __shared__ int h[NB];
    __shared__ int cur[NB];
    int base = blockIdx.x * EBLK;
    int n = NE - base; if (n > EBLK) n = EBLK;
    for (int i = threadIdx.x; i < NB; i += 256) h[i] = 0;
    __syncthreads();
    for (int i = threadIdx.x; i < n; i += 256)
        atomicAdd(&h[dstv[base + i] >> BSH], 1);
    __syncthreads();
    for (int b = threadIdx.x; b < NB; b += 256) {
        int c = h[b];
        cur[b] = c ? atomicAdd(&bucket_cursor[b], c) : 0;
    }
    __syncthreads();
    for (int i = threadIdx.x; i < n; i += 256) {
        int s = srcv[base + i], d = dstv[base + i];
        int b = d >> BSH;
        int pos = atomicAdd(&cur[b], 1);
        ppack[pos] = ((d & 255) << 17) | s;   // src < 2^17
    }
}

// One block per bucket: LDS counting sort over the 256-node range.
// Emits row_start for its nodes AND the final csr_src (bucket-local writes).
__global__ __launch_bounds__(256) void fillcsr_k(const int* __restrict__ bucket_base,
                                                 const int* __restrict__ ppack,
                                                 int* __restrict__ row_start,
                                                 int* __restrict__ csr_src) {
    __shared__ int cnt[256];
    __shared__ int scn[256];
    int b = blockIdx.x, t = threadIdx.x;
    int ebeg = bucket_base[b], eend = bucket_base[b + 1];
    cnt[t] = 0;
    __syncthreads();
    for (int i = ebeg + t; i < eend; i += 256)
        atomicAdd(&cnt[(ppack[i] >> 17) & 255], 1);
    __syncthreads();
    int v = cnt[t];
    scn[t] = v;
    __syncthreads();
    for (int off = 1; off < 256; off <<= 1) {
        int u = (t >= off) ? scn[t - off] : 0;
        __syncthreads();
        scn[t] += u;
        __syncthreads();
    }
    int ex = scn[t] - v;                      // exclusive prefix
    int node = (b << BSH) + t;
    if (node < NN) row_start[node] = ebeg + ex;
    cnt[t] = ex;                              // reuse as cursor
    __syncthreads();
    for (int i = ebeg + t; i < eend; i += 256) {
        int p = ppack[i];
        int pos = ebeg + atomicAdd(&cnt[(p >> 17) & 255], 1);
        csr_src[pos] = p & 0x1FFFF;
    }
    if (b == NB - 1 && t == 0) row_start[NN] = NE;
}

// ---------------- W prep: transpose + bf16 split + swizzle ----------------

__global__ __launch_bounds__(256) void prepw_k(const float* __restrict__ WL,
                                               const float* __restrict__ WR,
                                               ushort* __restrict__ wtL,
                                               ushort* __restrict__ wtR) {
    int t = gtid();
    if (t >= 2 * D * D) return;
    const float* W  = (t < D * D) ? WL : WR;
    ushort*      wt = (t < D * D) ? wtL : wtR;
    int e = t & (D * D - 1);
    int k = e >> 7, c = e & 127;
    float w = W[e];
    __bf16 hi = (__bf16)w;
    __bf16 lo = (__bf16)(w - (float)hi);
    int byte = c * 256 + ((k * 2) ^ ((c & 7) << 4));
    *(ushort*)((char*)wt + byte)         = __builtin_bit_cast(ushort, hi);
    *(ushort*)((char*)wt + 32768 + byte) = __builtin_bit_cast(ushort, lo);
}

// ---------------- layer-1 GEMM: split-bf16 MFMA ----------------

__global__ __launch_bounds__(512, 1) void mmL1_k(const float* __restrict__ X,
                                                 const ushort* __restrict__ wtL,
                                                 const ushort* __restrict__ wtR,
                                                 const float* __restrict__ b1,
                                                 float* __restrict__ outL,
                                                 float* __restrict__ outR) {
    __shared__ ushort s_xh[128 * 128];    // 32 KiB
    __shared__ ushort s_xl[128 * 128];    // 32 KiB
    __shared__ ushort s_w[2 * 128 * 128]; // 64 KiB (hi | lo)
    const int tid = threadIdx.x;
    const int wv = tid >> 6, ln = tid & 63;
    const int lr = ln & 15, lg = ln >> 4;
    const int r0 = blockIdx.x * 128;

    const float4* X4 = (const float4*)X;
#pragma unroll
    for (int it = 0; it < 8; ++it) {
        int v  = it * 512 + tid;
        int r  = v >> 5, kq = v & 31;
        int gr = r0 + r; if (gr >= NN) gr = NN - 1;
        float4 xv = X4[(size_t)gr * 32 + kq];
        bf16x4 hi, lo;
#pragma unroll
        for (int j = 0; j < 4; ++j) {
            float f = ((const float*)&xv)[j];
            __bf16 h = (__bf16)f;
            hi[j] = h;
            lo[j] = (__bf16)(f - (float)h);
        }
        int byte = r * 256 + ((kq * 8) ^ ((r & 7) << 4));
        *(bf16x4*)((char*)s_xh + byte) = hi;
        *(bf16x4*)((char*)s_xl + byte) = lo;
    }

    const int swzA = (((wv * 16 + lr) & 7) << 4);
    const int rowA = wv * 16 + lr;
    const int swzB = ((lr & 7) << 4);

#pragma unroll 1
    for (int pass = 0; pass < 2; ++pass) {
        const char* wsrc = (const char*)(pass ? wtR : wtL) + ln * 16;
#pragma unroll
        for (int c2 = 0; c2 < 8; ++c2) {
            int chunk = wv * 8 + c2;
            __builtin_amdgcn_global_load_lds(AS1(wsrc + chunk * 1024),
                                             AS3((char*)s_w + chunk * 1024),
                                             16, 0, 0);
        }
        __syncthreads();

        f32x4 acc[8];
#pragma unroll
        for (int nt = 0; nt < 8; ++nt) acc[nt] = f32x4{0.f, 0.f, 0.f, 0.f};

#pragma unroll
        for (int ks = 0; ks < 4; ++ks) {
            int kb = ks * 64 + lg * 16;
            int offA = rowA * 256 + (kb ^ swzA);
            bf16x8 ah = *(const bf16x8*)((const char*)s_xh + offA);
            bf16x8 al = *(const bf16x8*)((const char*)s_xl + offA);
#pragma unroll
            for (int nt = 0; nt < 8; ++nt) {
                int offB = (nt * 16 + lr) * 256 + (kb ^ swzB);
                bf16x8 bh = *(const bf16x8*)((const char*)s_w + offB);
                bf16x8 bl = *(const bf16x8*)((const char*)s_w + 32768 + offB);
                acc[nt] = __builtin_amdgcn_mfma_f32_16x16x32_bf16(ah, bh, acc[nt], 0, 0, 0);
                acc[nt] = __builtin_amdgcn_mfma_f32_16x16x32_bf16(ah, bl, acc[nt], 0, 0, 0);
                acc[nt] = __builtin_amdgcn_mfma_f32_16x16x32_bf16(al, bh, acc[nt], 0, 0, 0);
            }
        }

        float* outp = pass ? outR : outL;
        float bb[8];
#pragma unroll
        for (int nt = 0; nt < 8; ++nt) bb[nt] = pass ? b1[nt * 16 + lr] : 0.f;
#pragma unroll
        for (int j = 0; j < 4; ++j) {
            int gr = r0 + wv * 16 + lg * 4 + j;
            if (gr < NN) {
#pragma unroll
                for (int nt = 0; nt < 8; ++nt)
                    outp[(size_t)gr * D + nt * 16 + lr] = acc[nt][j] + bb[nt];
            }
        }
        __syncthreads();
    }
}

// ---------------- layer-2 GEMM: 64-row tile, fused [W2L|W2R] ----------------

__global__ __launch_bounds__(256) void mm16_k(const float* __restrict__ H,
                                              const float* __restrict__ W2L,
                                              const float* __restrict__ W2R,
                                              const float* __restrict__ B2,
                                              float* __restrict__ hl,
                                              float* __restrict__ hr) {
    __shared__ float4 xs[64 * 32];
    __shared__ float2 ws[128 * 16];
    const int tid = threadIdx.x;
    const int tx = tid & 15, ty = tid >> 4;
    const int r0 = blockIdx.x * 64;

    const float4* H4 = (const float4*)H;
#pragma unroll
    for (int it = 0; it < 8; ++it) {
        int v  = tid + it * 256;
        int r  = v >> 5, kb = v & 31;
        int gr = r0 + r; if (gr >= NN) gr = NN - 1;
        xs[r * 32 + (kb ^ ((r >> 2) & 3))] = H4[(size_t)gr * 32 + kb];
    }
    const float2* L2 = (const float2*)W2L;
    const float2* R2 = (const float2*)W2R;
#pragma unroll
    for (int it = 0; it < 4; ++it) {
        int v = tid + it * 256;
        int k = v >> 3, cc2 = v & 7;
        ws[k * 16 + cc2]     = L2[v];
        ws[k * 16 + 8 + cc2] = R2[v];
    }
    __syncthreads();

    float acc[4][2] = {};
#pragma unroll 1
    for (int ks = 0; ks < 32; ++ks) {
        float4 xa[4];
        float2 wb[4];
        int kx = ks ^ (ty & 3);
#pragma unroll
        for (int i = 0; i < 4; ++i) xa[i] = xs[(ty * 4 + i) * 32 + kx];
#pragma unroll
        for (int kk = 0; kk < 4; ++kk) wb[kk] = ws[(ks * 4 + kk) * 16 + tx];
#pragma unroll
        for (int kk = 0; kk < 4; ++kk)
#pragma unroll
            for (int i = 0; i < 4; ++i) {
                float xv = ((const float*)&xa[i])[kk];
                acc[i][0] += xv * wb[kk].x;
                acc[i][1] += xv * wb[kk].y;
            }
    }

#pragma unroll
    for (int i = 0; i < 4; ++i) {
        int gr = r0 + ty * 4 + i;
        if (gr >= NN) continue;
        if (tx < 8) {
            hl[(size_t)gr * NC + tx * 2]     = acc[i][0];
            hl[(size_t)gr * NC + tx * 2 + 1] = acc[i][1];
        } else {
            int c = (tx - 8) * 2;
            hr[(size_t)gr * NC + c]     = acc[i][0] + B2[c];
            hr[(size_t)gr * NC + c + 1] = acc[i][1] + B2[c + 1];
        }
    }
}

// ---------------- aggregation ----------------

__global__ __launch_bounds__(256) void agg1_k(const float* __restrict__ xl,
                                              const float* __restrict__ xr,
                                              const int* __restrict__ row_start,
                                              const int* __restrict__ csr_src,
                                              float* __restrict__ h) {
    int node = (blockIdx.x * blockDim.x + threadIdx.x) >> 6;
    int lane = threadIdx.x & 63;
    if (node >= NN) return;
    int beg = row_start[node], end = row_start[node + 1];
    const float2* xl2 = (const float2*)xl;
    float ax0 = 0.f, ay0 = 0.f, ax1 = 0.f, ay1 = 0.f;
    float ax2 = 0.f, ay2 = 0.f, ax3 = 0.f, ay3 = 0.f;
    int j = beg;
    for (; j + 3 < end; j += 4) {
        int s0 = csr_src[j], s1 = csr_src[j + 1];
        int s2 = csr_src[j + 2], s3 = csr_src[j + 3];
        float2 v0 = xl2[(size_t)s0 * 64 + lane];
        float2 v1 = xl2[(size_t)s1 * 64 + lane];
        float2 v2 = xl2[(size_t)s2 * 64 + lane];
        float2 v3 = xl2[(size_t)s3 * 64 + lane];
        ax0 += v0.x; ay0 += v0.y; ax1 += v1.x; ay1 += v1.y;
        ax2 += v2.x; ay2 += v2.y; ax3 += v3.x; ay3 += v3.y;
    }
    for (; j < end; ++j) {
        float2 v = xl2[(size_t)csr_src[j] * 64 + lane];
        ax0 += v.x; ay0 += v.y;
    }
    float ax = (ax0 + ax1) + (ax2 + ax3);
    float ay = (ay0 + ay1) + (ay2 + ay3);
    float inv = 1.f / fmaxf((float)(end - beg), 1.f);
    float2 r = ((const float2*)xr)[(size_t)node * 64 + lane];
    float2 o;
    o.x = fmaxf(ax * inv + r.x, 0.f);
    o.y = fmaxf(ay * inv + r.y, 0.f);
    ((float2*)h)[(size_t)node * 64 + lane] = o;
}

__global__ __launch_bounds__(256) void agg2_k(const float* __restrict__ hl,
                                              const float* __restrict__ hr,
                                              const int* __restrict__ row_start,
                                              const int* __restrict__ csr_src,
                                              float* __restrict__ out) {
    int node = (blockIdx.x * blockDim.x + threadIdx.x) >> 6;
    int lane = threadIdx.x & 63;
    if (node >= NN) return;
    int c = lane & 15, g = lane >> 4;
    int beg = row_start[node], end = row_start[node + 1];
    float acc = 0.f;
    for (int j = beg + g; j < end; j += 4)
        acc += hl[(size_t)csr_src[j] * NC + c];
    acc += __shfl_xor(acc, 16);
    acc += __shfl_xor(acc, 32);
    float inv = 1.f / fmaxf((float)(end - beg), 1.f);
    float o = acc * inv + hr[(size_t)node * NC + c];
    float m = o;
#pragma unroll
    for (int d = 1; d < 16; d <<= 1) m = fmaxf(m, __shfl_xor(m, d));
    float e = expf(o - m);
    float s = e;
#pragma unroll
    for (int d = 1; d < 16; d <<= 1) s += __shfl_xor(s, d);
    float res = o - m - logf(s);
    if (lane < 16) out[(size_t)node * NC + c] = res;
}

// ---------------- launch ----------------

extern "C" void kernel_launch(void* const* d_in, const int* in_sizes, int n_in,
                              void* d_out, int out_size, void* d_ws, size_t ws_size,
                              hipStream_t stream) {
    const float* x   = (const float*)d_in[0];
    const int*   ei  = (const int*)d_in[1];
    const float* w1l = (const float*)d_in[2];
    const float* w1r = (const float*)d_in[3];
    const float* b1  = (const float*)d_in[4];
    const float* w2l = (const float*)d_in[5];
    const float* w2r = (const float*)d_in[6];
    const float* b2  = (const float*)d_in[7];
    float* out = (float*)d_out;
    const int* srcv = ei;        // edge_index[0]
    const int* dstv = ei + NE;   // edge_index[1]

    char* p = (char*)d_ws;
    auto carve = [&](size_t bytes) -> void* {
        void* r = (void*)p;
        p += (bytes + 255) & ~(size_t)255;
        return r;
    };
    float*  xl        = (float*)carve(sizeof(float) * (size_t)NN * D);
    float*  xr        = (float*)carve(sizeof(float) * (size_t)NN * D);
    float*  h         = (float*)carve(sizeof(float) * (size_t)NN * D);
    float*  hl        = (float*)carve(sizeof(float) * (size_t)NN * NC);
    float*  hr        = (float*)carve(sizeof(float) * (size_t)NN * NC);
    int*    csr_src   = (int*)carve(sizeof(int) * (size_t)NE);
    int*    row_start = (int*)carve(sizeof(int) * (NN + 32));
    int*    bucket_cnt    = (int*)carve(sizeof(int) * (NB + 32));
    int*    bucket_base   = (int*)carve(sizeof(int) * (NB + 32));
    int*    bucket_cursor = (int*)carve(sizeof(int) * (NB + 32));
    ushort* wtL       = (ushort*)carve(sizeof(ushort) * 2 * D * D);
    ushort* wtR       = (ushort*)carve(sizeof(ushort) * 2 * D * D);
    // ppack aliases h: both are live only in disjoint phases (ppack dead
    // before agg1 writes h; same-stream ordering guarantees sequencing).
    int*    ppack     = (int*)h;

    hipMemsetAsync(bucket_cnt, 0, sizeof(int) * NB, stream);

    hist_k<<<256, 256, 0, stream>>>(dstv, bucket_cnt);
    scanb_k<<<1, 512, 0, stream>>>(bucket_cnt, bucket_base, bucket_cursor);
    part_k<<<(NE + EBLK - 1) / EBLK, 256, 0, stream>>>(srcv, dstv, bucket_cursor, ppack);
    fillcsr_k<<<NB, 256, 0, stream>>>(bucket_base, ppack, row_start, csr_src);

    prepw_k<<<128, 256, 0, stream>>>(w1l, w1r, wtL, wtR);
    mmL1_k<<<782, 512, 0, stream>>>(x, wtL, wtR, b1, xl, xr);
    agg1_k<<<25000, 256, 0, stream>>>(xl, xr, row_start, csr_src, h);

    mm16_k<<<1563, 256, 0, stream>>>(h, w2l, w2r, b2, hl, hr);
    agg2_k<<<25000, 256, 0, stream>>>(hl, hr, row_start, csr_src, out);
}

// Round 9
// 363.895 us; speedup vs baseline: 2.7067x; 1.1358x over previous
//
#include <hip/hip_runtime.h>

// GraphSAGE 2-layer forward on MI355X.
//  - CSR build via 2-level counting sort (r3->r6: fill_k 133us removed; 17x
//    write-amp eliminated).
//  - Layer 1: split-bf16 MFMA GEMM (x=hi+lo, W=hi+lo; 3 MFMA terms, f32 acc).
//    xl is stored BF16 (r6: agg1 gather was 403MB HBM fetch at 122us; bf16
//    halves bytes/row 512->256, all 64B lines still fully used). xr stays f32.
//  - agg1: wave-per-node gather-mean over bf16 xl + f32 xr + relu (4-deep ILP).
//  - Layer 2 transform-first (VALU, 16-wide), wave-per-node gather +
//    fused log_softmax.
// (Round 8 resubmission: r7 container-failed twice, r8 acquisition timeout —
//  the bf16-xl delta has never been measured; kernel unchanged for clean A/B
//  against r6's 413us / agg1 122us / FETCH 403MB.)

#define NN 100000
#define NE 1600000
#define D  128
#define NC 16

#define BSH 8                 // bucket shift: 256 nodes / bucket
#define NB  391               // ceil(NN / 256)
#define EBLK 8192             // edges per partition block

typedef unsigned short ushort;
typedef unsigned int   uint;
typedef __bf16 bf16x8 __attribute__((ext_vector_type(8)));
typedef __bf16 bf16x4 __attribute__((ext_vector_type(4)));
typedef float  f32x4  __attribute__((ext_vector_type(4)));

#define AS1(p) ((const __attribute__((address_space(1))) void*)(p))
#define AS3(p) ((__attribute__((address_space(3))) void*)(p))

__device__ __forceinline__ int gtid() { return blockIdx.x * blockDim.x + threadIdx.x; }

// ---------------- CSR build: 2-level counting sort ----------------

__global__ __launch_bounds__(256) void hist_k(const int* __restrict__ dstv,
                                              int* __restrict__ bucket_cnt) {
    __shared__ int h[NB];
    for (int i = threadIdx.x; i < NB; i += 256) h[i] = 0;
    __syncthreads();
    for (int i = gtid(); i < NE; i += gridDim.x * blockDim.x)
        atomicAdd(&h[dstv[i] >> BSH], 1);
    __syncthreads();
    for (int i = threadIdx.x; i < NB; i += 256)
        if (h[i]) atomicAdd(&bucket_cnt[i], h[i]);
}

__global__ __launch_bounds__(512) void scanb_k(const int* __restrict__ bucket_cnt,
                                               int* __restrict__ bucket_base,
                                               int* __restrict__ bucket_cursor) {
    __shared__ int arr[512];
    int t = threadIdx.x;
    int v = (t < NB) ? bucket_cnt[t] : 0;
    arr[t] = v;
    __syncthreads();
    for (int off = 1; off < 512; off <<= 1) {
        int u = (t >= off) ? arr[t - off] : 0;
        __syncthreads();
        arr[t] += u;
        __syncthreads();
    }
    if (t < NB) {
        int e = arr[t] - v;        // exclusive
        bucket_base[t]   = e;
        bucket_cursor[t] = e;
    }
    if (t == 0) bucket_base[NB] = NE;
}

// Partition edges by bucket; write one packed int per edge. Within a block
// each bucket's positions are consecutive -> write streams are sequential.
__global__ __launch_bounds__(256) void part_k(const int* __restrict__ srcv,
                                              const int* __restrict__ dstv,
                                              int* __restrict__ bucket_cursor,
                                              int* __restrict__ ppack) {
    __shared__ int h[NB];
    __shared__ int cur[NB];
    int base = blockIdx.x * EBLK;
    int n = NE - base; if (n > EBLK) n = EBLK;
    for (int i = threadIdx.x; i < NB; i += 256) h[i] = 0;
    __syncthreads();
    for (int i = threadIdx.x; i < n; i += 256)
        atomicAdd(&h[dstv[base + i] >> BSH], 1);
    __syncthreads();
    for (int b = threadIdx.x; b < NB; b += 256) {
        int c = h[b];
        cur[b] = c ? atomicAdd(&bucket_cursor[b], c) : 0;
    }
    __syncthreads();
    for (int i = threadIdx.x; i < n; i += 256) {
        int s = srcv[base + i], d = dstv[base + i];
        int b = d >> BSH;
        int pos = atomicAdd(&cur[b], 1);
        ppack[pos] = ((d & 255) << 17) | s;   // src < 2^17
    }
}

// One block per bucket: LDS counting sort over the 256-node range.
// Emits row_start for its nodes AND the final csr_src (bucket-local writes).
__global__ __launch_bounds__(256) void fillcsr_k(const int* __restrict__ bucket_base,
                                                 const int* __restrict__ ppack,
                                                 int* __restrict__ row_start,
                                                 int* __restrict__ csr_src) {
    __shared__ int cnt[256];
    __shared__ int scn[256];
    int b = blockIdx.x, t = threadIdx.x;
    int ebeg = bucket_base[b], eend = bucket_base[b + 1];
    cnt[t] = 0;
    __syncthreads();
    for (int i = ebeg + t; i < eend; i += 256)
        atomicAdd(&cnt[(ppack[i] >> 17) & 255], 1);
    __syncthreads();
    int v = cnt[t];
    scn[t] = v;
    __syncthreads();
    for (int off = 1; off < 256; off <<= 1) {
        int u = (t >= off) ? scn[t - off] : 0;
        __syncthreads();
        scn[t] += u;
        __syncthreads();
    }
    int ex = scn[t] - v;                      // exclusive prefix
    int node = (b << BSH) + t;
    if (node < NN) row_start[node] = ebeg + ex;
    cnt[t] = ex;                              // reuse as cursor
    __syncthreads();
    for (int i = ebeg + t; i < eend; i += 256) {
        int p = ppack[i];
        int pos = ebeg + atomicAdd(&cnt[(p >> 17) & 255], 1);
        csr_src[pos] = p & 0x1FFFF;
    }
    if (b == NB - 1 && t == 0) row_start[NN] = NE;
}

// ---------------- W prep: transpose + bf16 split + swizzle ----------------

__global__ __launch_bounds__(256) void prepw_k(const float* __restrict__ WL,
                                               const float* __restrict__ WR,
                                               ushort* __restrict__ wtL,
                                               ushort* __restrict__ wtR) {
    int t = gtid();
    if (t >= 2 * D * D) return;
    const float* W  = (t < D * D) ? WL : WR;
    ushort*      wt = (t < D * D) ? wtL : wtR;
    int e = t & (D * D - 1);
    int k = e >> 7, c = e & 127;
    float w = W[e];
    __bf16 hi = (__bf16)w;
    __bf16 lo = (__bf16)(w - (float)hi);
    int byte = c * 256 + ((k * 2) ^ ((c & 7) << 4));
    *(ushort*)((char*)wt + byte)         = __builtin_bit_cast(ushort, hi);
    *(ushort*)((char*)wt + 32768 + byte) = __builtin_bit_cast(ushort, lo);
}

// ---------------- layer-1 GEMM: split-bf16 MFMA ----------------

// pass 0 -> xl (bf16 output, no bias); pass 1 -> xr (f32 output, +b1).
__global__ __launch_bounds__(512, 1) void mmL1_k(const float* __restrict__ X,
                                                 const ushort* __restrict__ wtL,
                                                 const ushort* __restrict__ wtR,
                                                 const float* __restrict__ b1,
                                                 ushort* __restrict__ outLb,
                                                 float* __restrict__ outR) {
    __shared__ ushort s_xh[128 * 128];    // 32 KiB
    __shared__ ushort s_xl[128 * 128];    // 32 KiB
    __shared__ ushort s_w[2 * 128 * 128]; // 64 KiB (hi | lo)
    const int tid = threadIdx.x;
    const int wv = tid >> 6, ln = tid & 63;
    const int lr = ln & 15, lg = ln >> 4;
    const int r0 = blockIdx.x * 128;

    const float4* X4 = (const float4*)X;
#pragma unroll
    for (int it = 0; it < 8; ++it) {
        int v  = it * 512 + tid;
        int r  = v >> 5, kq = v & 31;
        int gr = r0 + r; if (gr >= NN) gr = NN - 1;
        float4 xv = X4[(size_t)gr * 32 + kq];
        bf16x4 hi, lo;
#pragma unroll
        for (int j = 0; j < 4; ++j) {
            float f = ((const float*)&xv)[j];
            __bf16 h = (__bf16)f;
            hi[j] = h;
            lo[j] = (__bf16)(f - (float)h);
        }
        int byte = r * 256 + ((kq * 8) ^ ((r & 7) << 4));
        *(bf16x4*)((char*)s_xh + byte) = hi;
        *(bf16x4*)((char*)s_xl + byte) = lo;
    }

    const int swzA = (((wv * 16 + lr) & 7) << 4);
    const int rowA = wv * 16 + lr;
    const int swzB = ((lr & 7) << 4);

#pragma unroll 1
    for (int pass = 0; pass < 2; ++pass) {
        const char* wsrc = (const char*)(pass ? wtR : wtL) + ln * 16;
#pragma unroll
        for (int c2 = 0; c2 < 8; ++c2) {
            int chunk = wv * 8 + c2;
            __builtin_amdgcn_global_load_lds(AS1(wsrc + chunk * 1024),
                                             AS3((char*)s_w + chunk * 1024),
                                             16, 0, 0);
        }
        __syncthreads();

        f32x4 acc[8];
#pragma unroll
        for (int nt = 0; nt < 8; ++nt) acc[nt] = f32x4{0.f, 0.f, 0.f, 0.f};

#pragma unroll
        for (int ks = 0; ks < 4; ++ks) {
            int kb = ks * 64 + lg * 16;
            int offA = rowA * 256 + (kb ^ swzA);
            bf16x8 ah = *(const bf16x8*)((const char*)s_xh + offA);
            bf16x8 al = *(const bf16x8*)((const char*)s_xl + offA);
#pragma unroll
            for (int nt = 0; nt < 8; ++nt) {
                int offB = (nt * 16 + lr) * 256 + (kb ^ swzB);
                bf16x8 bh = *(const bf16x8*)((const char*)s_w + offB);
                bf16x8 bl = *(const bf16x8*)((const char*)s_w + 32768 + offB);
                acc[nt] = __builtin_amdgcn_mfma_f32_16x16x32_bf16(ah, bh, acc[nt], 0, 0, 0);
                acc[nt] = __builtin_amdgcn_mfma_f32_16x16x32_bf16(ah, bl, acc[nt], 0, 0, 0);
                acc[nt] = __builtin_amdgcn_mfma_f32_16x16x32_bf16(al, bh, acc[nt], 0, 0, 0);
            }
        }

        // C/D layout: col = lane&15, row = (lane>>4)*4 + reg
        if (pass == 0) {
#pragma unroll
            for (int j = 0; j < 4; ++j) {
                int gr = r0 + wv * 16 + lg * 4 + j;
                if (gr < NN) {
#pragma unroll
                    for (int nt = 0; nt < 8; ++nt) {
                        __bf16 v = (__bf16)acc[nt][j];
                        outLb[(size_t)gr * D + nt * 16 + lr] =
                            __builtin_bit_cast(ushort, v);
                    }
                }
            }
        } else {
            float bb[8];
#pragma unroll
            for (int nt = 0; nt < 8; ++nt) bb[nt] = b1[nt * 16 + lr];
#pragma unroll
            for (int j = 0; j < 4; ++j) {
                int gr = r0 + wv * 16 + lg * 4 + j;
                if (gr < NN) {
#pragma unroll
                    for (int nt = 0; nt < 8; ++nt)
                        outR[(size_t)gr * D + nt * 16 + lr] = acc[nt][j] + bb[nt];
                }
            }
        }
        __syncthreads();
    }
}

// ---------------- layer-2 GEMM: 64-row tile, fused [W2L|W2R] ----------------

__global__ __launch_bounds__(256) void mm16_k(const float* __restrict__ H,
                                              const float* __restrict__ W2L,
                                              const float* __restrict__ W2R,
                                              const float* __restrict__ B2,
                                              float* __restrict__ hl,
                                              float* __restrict__ hr) {
    __shared__ float4 xs[64 * 32];
    __shared__ float2 ws[128 * 16];
    const int tid = threadIdx.x;
    const int tx = tid & 15, ty = tid >> 4;
    const int r0 = blockIdx.x * 64;

    const float4* H4 = (const float4*)H;
#pragma unroll
    for (int it = 0; it < 8; ++it) {
        int v  = tid + it * 256;
        int r  = v >> 5, kb = v & 31;
        int gr = r0 + r; if (gr >= NN) gr = NN - 1;
        xs[r * 32 + (kb ^ ((r >> 2) & 3))] = H4[(size_t)gr * 32 + kb];
    }
    const float2* L2 = (const float2*)W2L;
    const float2* R2 = (const float2*)W2R;
#pragma unroll
    for (int it = 0; it < 4; ++it) {
        int v = tid + it * 256;
        int k = v >> 3, cc2 = v & 7;
        ws[k * 16 + cc2]     = L2[v];
        ws[k * 16 + 8 + cc2] = R2[v];
    }
    __syncthreads();

    float acc[4][2] = {};
#pragma unroll 1
    for (int ks = 0; ks < 32; ++ks) {
        float4 xa[4];
        float2 wb[4];
        int kx = ks ^ (ty & 3);
#pragma unroll
        for (int i = 0; i < 4; ++i) xa[i] = xs[(ty * 4 + i) * 32 + kx];
#pragma unroll
        for (int kk = 0; kk < 4; ++kk) wb[kk] = ws[(ks * 4 + kk) * 16 + tx];
#pragma unroll
        for (int kk = 0; kk < 4; ++kk)
#pragma unroll
            for (int i = 0; i < 4; ++i) {
                float xv = ((const float*)&xa[i])[kk];
                acc[i][0] += xv * wb[kk].x;
                acc[i][1] += xv * wb[kk].y;
            }
    }

#pragma unroll
    for (int i = 0; i < 4; ++i) {
        int gr = r0 + ty * 4 + i;
        if (gr >= NN) continue;
        if (tx < 8) {
            hl[(size_t)gr * NC + tx * 2]     = acc[i][0];
            hl[(size_t)gr * NC + tx * 2 + 1] = acc[i][1];
        } else {
            int c = (tx - 8) * 2;
            hr[(size_t)gr * NC + c]     = acc[i][0] + B2[c];
            hr[(size_t)gr * NC + c + 1] = acc[i][1] + B2[c + 1];
        }
    }
}

// ---------------- aggregation ----------------

// Wave per node: h[i] = relu(mean_j xlb[src_j] + xr[i]); xlb is bf16-packed,
// lane reads one uint (2 bf16) -> 256B/row gather (halved vs f32).
__global__ __launch_bounds__(256) void agg1_k(const ushort* __restrict__ xlb,
                                              const float* __restrict__ xr,
                                              const int* __restrict__ row_start,
                                              const int* __restrict__ csr_src,
                                              float* __restrict__ h) {
    int node = (blockIdx.x * blockDim.x + threadIdx.x) >> 6;
    int lane = threadIdx.x & 63;
    if (node >= NN) return;
    int beg = row_start[node], end = row_start[node + 1];
    const uint* xlu = (const uint*)xlb;   // 64 uints per row
    float ax0 = 0.f, ay0 = 0.f, ax1 = 0.f, ay1 = 0.f;
    float ax2 = 0.f, ay2 = 0.f, ax3 = 0.f, ay3 = 0.f;
    int j = beg;
    for (; j + 3 < end; j += 4) {   // 4 independent gathers in flight
        int s0 = csr_src[j], s1 = csr_src[j + 1];
        int s2 = csr_src[j + 2], s3 = csr_src[j + 3];
        uint u0 = xlu[(size_t)s0 * 64 + lane];
        uint u1 = xlu[(size_t)s1 * 64 + lane];
        uint u2 = xlu[(size_t)s2 * 64 + lane];
        uint u3 = xlu[(size_t)s3 * 64 + lane];
        ax0 += __builtin_bit_cast(float, u0 << 16);
        ay0 += __builtin_bit_cast(float, u0 & 0xFFFF0000u);
        ax1 += __builtin_bit_cast(float, u1 << 16);
        ay1 += __builtin_bit_cast(float, u1 & 0xFFFF0000u);
        ax2 += __builtin_bit_cast(float, u2 << 16);
        ay2 += __builtin_bit_cast(float, u2 & 0xFFFF0000u);
        ax3 += __builtin_bit_cast(float, u3 << 16);
        ay3 += __builtin_bit_cast(float, u3 & 0xFFFF0000u);
    }
    for (; j < end; ++j) {
        uint u = xlu[(size_t)csr_src[j] * 64 + lane];
        ax0 += __builtin_bit_cast(float, u << 16);
        ay0 += __builtin_bit_cast(float, u & 0xFFFF0000u);
    }
    float ax = (ax0 + ax1) + (ax2 + ax3);
    float ay = (ay0 + ay1) + (ay2 + ay3);
    float inv = 1.f / fmaxf((float)(end - beg), 1.f);
    float2 r = ((const float2*)xr)[(size_t)node * 64 + lane];
    float2 o;
    o.x = fmaxf(ax * inv + r.x, 0.f);
    o.y = fmaxf(ay * inv + r.y, 0.f);
    ((float2*)h)[(size_t)node * 64 + lane] = o;
}

__global__ __launch_bounds__(256) void agg2_k(const float* __restrict__ hl,
                                              const float* __restrict__ hr,
                                              const int* __restrict__ row_start,
                                              const int* __restrict__ csr_src,
                                              float* __restrict__ out) {
    int node = (blockIdx.x * blockDim.x + threadIdx.x) >> 6;
    int lane = threadIdx.x & 63;
    if (node >= NN) return;
    int c = lane & 15, g = lane >> 4;
    int beg = row_start[node], end = row_start[node + 1];
    float acc = 0.f;
    for (int j = beg + g; j < end; j += 4)
        acc += hl[(size_t)csr_src[j] * NC + c];
    acc += __shfl_xor(acc, 16);
    acc += __shfl_xor(acc, 32);
    float inv = 1.f / fmaxf((float)(end - beg), 1.f);
    float o = acc * inv + hr[(size_t)node * NC + c];
    float m = o;
#pragma unroll
    for (int d = 1; d < 16; d <<= 1) m = fmaxf(m, __shfl_xor(m, d));
    float e = expf(o - m);
    float s = e;
#pragma unroll
    for (int d = 1; d < 16; d <<= 1) s += __shfl_xor(s, d);
    float res = o - m - logf(s);
    if (lane < 16) out[(size_t)node * NC + c] = res;
}

// ---------------- launch ----------------

extern "C" void kernel_launch(void* const* d_in, const int* in_sizes, int n_in,
                              void* d_out, int out_size, void* d_ws, size_t ws_size,
                              hipStream_t stream) {
    const float* x   = (const float*)d_in[0];
    const int*   ei  = (const int*)d_in[1];
    const float* w1l = (const float*)d_in[2];
    const float* w1r = (const float*)d_in[3];
    const float* b1  = (const float*)d_in[4];
    const float* w2l = (const float*)d_in[5];
    const float* w2r = (const float*)d_in[6];
    const float* b2  = (const float*)d_in[7];
    float* out = (float*)d_out;
    const int* srcv = ei;        // edge_index[0]
    const int* dstv = ei + NE;   // edge_index[1]

    char* p = (char*)d_ws;
    auto carve = [&](size_t bytes) -> void* {
        void* r = (void*)p;
        p += (bytes + 255) & ~(size_t)255;
        return r;
    };
    ushort* xlb       = (ushort*)carve(sizeof(ushort) * (size_t)NN * D);
    float*  xr        = (float*)carve(sizeof(float) * (size_t)NN * D);
    float*  h         = (float*)carve(sizeof(float) * (size_t)NN * D);
    float*  hl        = (float*)carve(sizeof(float) * (size_t)NN * NC);
    float*  hr        = (float*)carve(sizeof(float) * (size_t)NN * NC);
    int*    csr_src   = (int*)carve(sizeof(int) * (size_t)NE);
    int*    row_start = (int*)carve(sizeof(int) * (NN + 32));
    int*    bucket_cnt    = (int*)carve(sizeof(int) * (NB + 32));
    int*    bucket_base   = (int*)carve(sizeof(int) * (NB + 32));
    int*    bucket_cursor = (int*)carve(sizeof(int) * (NB + 32));
    ushort* wtL       = (ushort*)carve(sizeof(ushort) * 2 * D * D);
    ushort* wtR       = (ushort*)carve(sizeof(ushort) * 2 * D * D);
    // ppack aliases h: both are live only in disjoint phases (ppack dead
    // before agg1 writes h; same-stream ordering guarantees sequencing).
    int*    ppack     = (int*)h;

    hipMemsetAsync(bucket_cnt, 0, sizeof(int) * NB, stream);

    hist_k<<<256, 256, 0, stream>>>(dstv, bucket_cnt);
    scanb_k<<<1, 512, 0, stream>>>(bucket_cnt, bucket_base, bucket_cursor);
    part_k<<<(NE + EBLK - 1) / EBLK, 256, 0, stream>>>(srcv, dstv, bucket_cursor, ppack);
    fillcsr_k<<<NB, 256, 0, stream>>>(bucket_base, ppack, row_start, csr_src);

    prepw_k<<<128, 256, 0, stream>>>(w1l, w1r, wtL, wtR);
    mmL1_k<<<782, 512, 0, stream>>>(x, wtL, wtR, b1, xlb, xr);
    agg1_k<<<25000, 256, 0, stream>>>(xlb, xr, row_start, csr_src, h);

    mm16_k<<<1563, 256, 0, stream>>>(h, w2l, w2r, b2, hl, hr);
    agg2_k<<<25000, 256, 0, stream>>>(hl, hr, row_start, csr_src, out);
}

// Round 11
// 346.948 us; speedup vs baseline: 2.8389x; 1.0488x over previous
//
#include <hip/hip_runtime.h>

// GraphSAGE 2-layer forward on MI355X.
//  - CSR build via 2-level counting sort (r3->r6: 17x write-amp eliminated).
//  - Layer 1: split-bf16 MFMA GEMM. xl stored FP8 e4m3 (r9: bf16-xl halved
//    agg1 traffic exactly as modeled; fp8 halves it again, 256->128 B/row;
//    error ~0.004 << 0.0156 quantum). xr stays f32.
//  - h stored bf16 (halves agg1 write + mm16 read).
//  - hl stored bf16 (3.2 MB -> fits one XCD L2 -> agg2 gathers become L2 hits).
//  - agg1: wave-per-node gather-mean (HW fp8 cvt, has_builtin fallback).
//  - Layer 2 transform-first, wave-per-node gather + fused log_softmax.
// (Round 10 resubmission: r10 bench failed on container infra — same error
//  signature as r7 which was also pure infra; kernel unchanged for clean A/B
//  against r9's 364us / agg1 78.7us / FETCH 207MB.)

#define NN 100000
#define NE 1600000
#define D  128
#define NC 16

#define BSH 8                 // bucket shift: 256 nodes / bucket
#define NB  391               // ceil(NN / 256)
#define EBLK 8192             // edges per partition block

typedef unsigned short ushort;
typedef unsigned int   uint;
typedef unsigned char  uchar;
typedef __bf16 bf16x8 __attribute__((ext_vector_type(8)));
typedef __bf16 bf16x4 __attribute__((ext_vector_type(4)));
typedef float  f32x4  __attribute__((ext_vector_type(4)));
typedef float  f32x2  __attribute__((ext_vector_type(2)));

#define AS1(p) ((const __attribute__((address_space(1))) void*)(p))
#define AS3(p) ((__attribute__((address_space(3))) void*)(p))

__device__ __forceinline__ int gtid() { return blockIdx.x * blockDim.x + threadIdx.x; }

// ---- fp8 e4m3 (OCP) helpers: HW cvt when available, bit-math fallback ----

__device__ __forceinline__ f32x2 fp8x2_to_f32(uint u) {
#if __has_builtin(__builtin_amdgcn_cvt_pk_f32_fp8)
    return __builtin_amdgcn_cvt_pk_f32_fp8((int)u, false);
#else
    f32x2 r;
    uint b0 = u & 0xFFu, b1 = (u >> 8) & 0xFFu;
    r.x = __builtin_bit_cast(float, ((b0 & 0x80u) << 24) | ((b0 & 0x7Fu) << 20)) * 0x1p120f;
    r.y = __builtin_bit_cast(float, ((b1 & 0x80u) << 24) | ((b1 & 0x7Fu) << 20)) * 0x1p120f;
    return r;
#endif
}

__device__ __forceinline__ uchar f32_to_fp8(float f) {
#if __has_builtin(__builtin_amdgcn_cvt_pk_fp8_f32)
    return (uchar)(__builtin_amdgcn_cvt_pk_fp8_f32(f, f, 0, false) & 0xFF);
#else
    uint s = (__builtin_bit_cast(uint, f) >> 24) & 0x80u;
    float a = fabsf(f) * 0x1p-120f;
    uint u = __builtin_bit_cast(uint, a);
    u = (u + 0x7FFFFu + ((u >> 20) & 1u)) >> 20;   // RNE to e4m3 grid
    if (u > 0x7Eu) u = 0x7Eu;                      // clamp to max finite
    return (uchar)(s | u);
#endif
}

__device__ __forceinline__ uint pack_bf16x2(float x, float y) {
    __bf16 bx = (__bf16)x, by = (__bf16)y;
    return (uint)__builtin_bit_cast(ushort, bx) |
           ((uint)__builtin_bit_cast(ushort, by) << 16);
}

// ---------------- CSR build: 2-level counting sort ----------------

__global__ __launch_bounds__(256) void hist_k(const int* __restrict__ dstv,
                                              int* __restrict__ bucket_cnt) {
    __shared__ int h[NB];
    for (int i = threadIdx.x; i < NB; i += 256) h[i] = 0;
    __syncthreads();
    for (int i = gtid(); i < NE; i += gridDim.x * blockDim.x)
        atomicAdd(&h[dstv[i] >> BSH], 1);
    __syncthreads();
    for (int i = threadIdx.x; i < NB; i += 256)
        if (h[i]) atomicAdd(&bucket_cnt[i], h[i]);
}

__global__ __launch_bounds__(512) void scanb_k(const int* __restrict__ bucket_cnt,
                                               int* __restrict__ bucket_base,
                                               int* __restrict__ bucket_cursor) {
    __shared__ int arr[512];
    int t = threadIdx.x;
    int v = (t < NB) ? bucket_cnt[t] : 0;
    arr[t] = v;
    __syncthreads();
    for (int off = 1; off < 512; off <<= 1) {
        int u = (t >= off) ? arr[t - off] : 0;
        __syncthreads();
        arr[t] += u;
        __syncthreads();
    }
    if (t < NB) {
        int e = arr[t] - v;        // exclusive
        bucket_base[t]   = e;
        bucket_cursor[t] = e;
    }
    if (t == 0) bucket_base[NB] = NE;
}

__global__ __launch_bounds__(256) void part_k(const int* __restrict__ srcv,
                                              const int* __restrict__ dstv,
                                              int* __restrict__ bucket_cursor,
                                              int* __restrict__ ppack) {
    __shared__ int h[NB];
    __shared__ int cur[NB];
    int base = blockIdx.x * EBLK;
    int n = NE - base; if (n > EBLK) n = EBLK;
    for (int i = threadIdx.x; i < NB; i += 256) h[i] = 0;
    __syncthreads();
    for (int i = threadIdx.x; i < n; i += 256)
        atomicAdd(&h[dstv[base + i] >> BSH], 1);
    __syncthreads();
    for (int b = threadIdx.x; b < NB; b += 256) {
        int c = h[b];
        cur[b] = c ? atomicAdd(&bucket_cursor[b], c) : 0;
    }
    __syncthreads();
    for (int i = threadIdx.x; i < n; i += 256) {
        int s = srcv[base + i], d = dstv[base + i];
        int b = d >> BSH;
        int pos = atomicAdd(&cur[b], 1);
        ppack[pos] = ((d & 255) << 17) | s;   // src < 2^17
    }
}

__global__ __launch_bounds__(256) void fillcsr_k(const int* __restrict__ bucket_base,
                                                 const int* __restrict__ ppack,
                                                 int* __restrict__ row_start,
                                                 int* __restrict__ csr_src) {
    __shared__ int cnt[256];
    __shared__ int scn[256];
    int b = blockIdx.x, t = threadIdx.x;
    int ebeg = bucket_base[b], eend = bucket_base[b + 1];
    cnt[t] = 0;
    __syncthreads();
    for (int i = ebeg + t; i < eend; i += 256)
        atomicAdd(&cnt[(ppack[i] >> 17) & 255], 1);
    __syncthreads();
    int v = cnt[t];
    scn[t] = v;
    __syncthreads();
    for (int off = 1; off < 256; off <<= 1) {
        int u = (t >= off) ? scn[t - off] : 0;
        __syncthreads();
        scn[t] += u;
        __syncthreads();
    }
    int ex = scn[t] - v;                      // exclusive prefix
    int node = (b << BSH) + t;
    if (node < NN) row_start[node] = ebeg + ex;
    cnt[t] = ex;                              // reuse as cursor
    __syncthreads();
    for (int i = ebeg + t; i < eend; i += 256) {
        int p = ppack[i];
        int pos = ebeg + atomicAdd(&cnt[(p >> 17) & 255], 1);
        csr_src[pos] = p & 0x1FFFF;
    }
    if (b == NB - 1 && t == 0) row_start[NN] = NE;
}

// ---------------- W prep: transpose + bf16 split + swizzle ----------------

__global__ __launch_bounds__(256) void prepw_k(const float* __restrict__ WL,
                                               const float* __restrict__ WR,
                                               ushort* __restrict__ wtL,
                                               ushort* __restrict__ wtR) {
    int t = gtid();
    if (t >= 2 * D * D) return;
    const float* W  = (t < D * D) ? WL : WR;
    ushort*      wt = (t < D * D) ? wtL : wtR;
    int e = t & (D * D - 1);
    int k = e >> 7, c = e & 127;
    float w = W[e];
    __bf16 hi = (__bf16)w;
    __bf16 lo = (__bf16)(w - (float)hi);
    int byte = c * 256 + ((k * 2) ^ ((c & 7) << 4));
    *(ushort*)((char*)wt + byte)         = __builtin_bit_cast(ushort, hi);
    *(ushort*)((char*)wt + 32768 + byte) = __builtin_bit_cast(ushort, lo);
}

// ---------------- layer-1 GEMM: split-bf16 MFMA ----------------

// pass 0 -> xl (fp8 output, no bias); pass 1 -> xr (f32 output, +b1).
__global__ __launch_bounds__(512, 1) void mmL1_k(const float* __restrict__ X,
                                                 const ushort* __restrict__ wtL,
                                                 const ushort* __restrict__ wtR,
                                                 const float* __restrict__ b1,
                                                 uchar* __restrict__ outL8,
                                                 float* __restrict__ outR) {
    __shared__ ushort s_xh[128 * 128];    // 32 KiB
    __shared__ ushort s_xl[128 * 128];    // 32 KiB
    __shared__ ushort s_w[2 * 128 * 128]; // 64 KiB (hi | lo)
    const int tid = threadIdx.x;
    const int wv = tid >> 6, ln = tid & 63;
    const int lr = ln & 15, lg = ln >> 4;
    const int r0 = blockIdx.x * 128;

    const float4* X4 = (const float4*)X;
#pragma unroll
    for (int it = 0; it < 8; ++it) {
        int v  = it * 512 + tid;
        int r  = v >> 5, kq = v & 31;
        int gr = r0 + r; if (gr >= NN) gr = NN - 1;
        float4 xv = X4[(size_t)gr * 32 + kq];
        bf16x4 hi, lo;
#pragma unroll
        for (int j = 0; j < 4; ++j) {
            float f = ((const float*)&xv)[j];
            __bf16 h = (__bf16)f;
            hi[j] = h;
            lo[j] = (__bf16)(f - (float)h);
        }
        int byte = r * 256 + ((kq * 8) ^ ((r & 7) << 4));
        *(bf16x4*)((char*)s_xh + byte) = hi;
        *(bf16x4*)((char*)s_xl + byte) = lo;
    }

    const int swzA = (((wv * 16 + lr) & 7) << 4);
    const int rowA = wv * 16 + lr;
    const int swzB = ((lr & 7) << 4);

#pragma unroll 1
    for (int pass = 0; pass < 2; ++pass) {
        const char* wsrc = (const char*)(pass ? wtR : wtL) + ln * 16;
#pragma unroll
        for (int c2 = 0; c2 < 8; ++c2) {
            int chunk = wv * 8 + c2;
            __builtin_amdgcn_global_load_lds(AS1(wsrc + chunk * 1024),
                                             AS3((char*)s_w + chunk * 1024),
                                             16, 0, 0);
        }
        __syncthreads();

        f32x4 acc[8];
#pragma unroll
        for (int nt = 0; nt < 8; ++nt) acc[nt] = f32x4{0.f, 0.f, 0.f, 0.f};

#pragma unroll
        for (int ks = 0; ks < 4; ++ks) {
            int kb = ks * 64 + lg * 16;
            int offA = rowA * 256 + (kb ^ swzA);
            bf16x8 ah = *(const bf16x8*)((const char*)s_xh + offA);
            bf16x8 al = *(const bf16x8*)((const char*)s_xl + offA);
#pragma unroll
            for (int nt = 0; nt < 8; ++nt) {
                int offB = (nt * 16 + lr) * 256 + (kb ^ swzB);
                bf16x8 bh = *(const bf16x8*)((const char*)s_w + offB);
                bf16x8 bl = *(const bf16x8*)((const char*)s_w + 32768 + offB);
                acc[nt] = __builtin_amdgcn_mfma_f32_16x16x32_bf16(ah, bh, acc[nt], 0, 0, 0);
                acc[nt] = __builtin_amdgcn_mfma_f32_16x16x32_bf16(ah, bl, acc[nt], 0, 0, 0);
                acc[nt] = __builtin_amdgcn_mfma_f32_16x16x32_bf16(al, bh, acc[nt], 0, 0, 0);
            }
        }

        // C/D layout: col = lane&15, row = (lane>>4)*4 + reg
        if (pass == 0) {
#pragma unroll
            for (int j = 0; j < 4; ++j) {
                int gr = r0 + wv * 16 + lg * 4 + j;
                if (gr < NN) {
#pragma unroll
                    for (int nt = 0; nt < 8; ++nt)
                        outL8[(size_t)gr * D + nt * 16 + lr] = f32_to_fp8(acc[nt][j]);
                }
            }
        } else {
            float bb[8];
#pragma unroll
            for (int nt = 0; nt < 8; ++nt) bb[nt] = b1[nt * 16 + lr];
#pragma unroll
            for (int j = 0; j < 4; ++j) {
                int gr = r0 + wv * 16 + lg * 4 + j;
                if (gr < NN) {
#pragma unroll
                    for (int nt = 0; nt < 8; ++nt)
                        outR[(size_t)gr * D + nt * 16 + lr] = acc[nt][j] + bb[nt];
                }
            }
        }
        __syncthreads();
    }
}

// ---------------- layer-2 GEMM: 64-row tile, fused [W2L|W2R] ----------------

// H is bf16 (row = 128 bf16 = 16 uint4); hl out bf16, hr out f32.
__global__ __launch_bounds__(256) void mm16_k(const ushort* __restrict__ Hb,
                                              const float* __restrict__ W2L,
                                              const float* __restrict__ W2R,
                                              const float* __restrict__ B2,
                                              ushort* __restrict__ hlb,
                                              float* __restrict__ hr) {
    __shared__ float4 xs[64 * 32];
    __shared__ float2 ws[128 * 16];
    const int tid = threadIdx.x;
    const int tx = tid & 15, ty = tid >> 4;
    const int r0 = blockIdx.x * 64;

    const uint4* H4 = (const uint4*)Hb;
#pragma unroll
    for (int it = 0; it < 4; ++it) {
        int v  = tid + it * 256;          // uint4 index 0..1023
        int r  = v >> 4, q = v & 15;
        int gr = r0 + r; if (gr >= NN) gr = NN - 1;
        uint4 u = H4[(size_t)gr * 16 + q];
        float4 a, b;
        a.x = __builtin_bit_cast(float, u.x << 16);
        a.y = __builtin_bit_cast(float, u.x & 0xFFFF0000u);
        a.z = __builtin_bit_cast(float, u.y << 16);
        a.w = __builtin_bit_cast(float, u.y & 0xFFFF0000u);
        b.x = __builtin_bit_cast(float, u.z << 16);
        b.y = __builtin_bit_cast(float, u.z & 0xFFFF0000u);
        b.z = __builtin_bit_cast(float, u.w << 16);
        b.w = __builtin_bit_cast(float, u.w & 0xFFFF0000u);
        int sw = (r >> 2) & 3;
        xs[r * 32 + ((2 * q) ^ sw)]     = a;
        xs[r * 32 + ((2 * q + 1) ^ sw)] = b;
    }
    const float2* L2 = (const float2*)W2L;
    const float2* R2 = (const float2*)W2R;
#pragma unroll
    for (int it = 0; it < 4; ++it) {
        int v = tid + it * 256;
        int k = v >> 3, cc2 = v & 7;
        ws[k * 16 + cc2]     = L2[v];
        ws[k * 16 + 8 + cc2] = R2[v];
    }
    __syncthreads();

    float acc[4][2] = {};
#pragma unroll 1
    for (int ks = 0; ks < 32; ++ks) {
        float4 xa[4];
        float2 wb[4];
        int kx = ks ^ (ty & 3);
#pragma unroll
        for (int i = 0; i < 4; ++i) xa[i] = xs[(ty * 4 + i) * 32 + kx];
#pragma unroll
        for (int kk = 0; kk < 4; ++kk) wb[kk] = ws[(ks * 4 + kk) * 16 + tx];
#pragma unroll
        for (int kk = 0; kk < 4; ++kk)
#pragma unroll
            for (int i = 0; i < 4; ++i) {
                float xv = ((const float*)&xa[i])[kk];
                acc[i][0] += xv * wb[kk].x;
                acc[i][1] += xv * wb[kk].y;
            }
    }

#pragma unroll
    for (int i = 0; i < 4; ++i) {
        int gr = r0 + ty * 4 + i;
        if (gr >= NN) continue;
        if (tx < 8) {
            ((uint*)hlb)[(size_t)gr * 8 + tx] = pack_bf16x2(acc[i][0], acc[i][1]);
        } else {
            int c = (tx - 8) * 2;
            hr[(size_t)gr * NC + c]     = acc[i][0] + B2[c];
            hr[(size_t)gr * NC + c + 1] = acc[i][1] + B2[c + 1];
        }
    }
}

// ---------------- aggregation ----------------

// Wave per node: h[i] = relu(mean_j xl8[src_j] + xr[i]); xl8 fp8 -> 128B/row
// gather; h written bf16-packed (1 uint per lane).
__global__ __launch_bounds__(256) void agg1_k(const uchar* __restrict__ xl8,
                                              const float* __restrict__ xr,
                                              const int* __restrict__ row_start,
                                              const int* __restrict__ csr_src,
                                              uint* __restrict__ hb) {
    int node = (blockIdx.x * blockDim.x + threadIdx.x) >> 6;
    int lane = threadIdx.x & 63;
    if (node >= NN) return;
    int beg = row_start[node], end = row_start[node + 1];
    const ushort* xlu = (const ushort*)xl8;   // 64 ushorts (2 fp8 each) per row
    float ax0 = 0.f, ay0 = 0.f, ax1 = 0.f, ay1 = 0.f;
    float ax2 = 0.f, ay2 = 0.f, ax3 = 0.f, ay3 = 0.f;
    int j = beg;
    for (; j + 3 < end; j += 4) {   // 4 independent gathers in flight
        int s0 = csr_src[j], s1 = csr_src[j + 1];
        int s2 = csr_src[j + 2], s3 = csr_src[j + 3];
        ushort u0 = xlu[(size_t)s0 * 64 + lane];
        ushort u1 = xlu[(size_t)s1 * 64 + lane];
        ushort u2 = xlu[(size_t)s2 * 64 + lane];
        ushort u3 = xlu[(size_t)s3 * 64 + lane];
        f32x2 f0 = fp8x2_to_f32(u0);
        f32x2 f1 = fp8x2_to_f32(u1);
        f32x2 f2 = fp8x2_to_f32(u2);
        f32x2 f3 = fp8x2_to_f32(u3);
        ax0 += f0.x; ay0 += f0.y;
        ax1 += f1.x; ay1 += f1.y;
        ax2 += f2.x; ay2 += f2.y;
        ax3 += f3.x; ay3 += f3.y;
    }
    for (; j < end; ++j) {
        f32x2 f = fp8x2_to_f32(xlu[(size_t)csr_src[j] * 64 + lane]);
        ax0 += f.x; ay0 += f.y;
    }
    float ax = (ax0 + ax1) + (ax2 + ax3);
    float ay = (ay0 + ay1) + (ay2 + ay3);
    float inv = 1.f / fmaxf((float)(end - beg), 1.f);
    float2 r = ((const float2*)xr)[(size_t)node * 64 + lane];
    float ox = fmaxf(ax * inv + r.x, 0.f);
    float oy = fmaxf(ay * inv + r.y, 0.f);
    hb[(size_t)node * 64 + lane] = pack_bf16x2(ox, oy);
}

// Wave per node: out[i] = log_softmax(mean_j hlb[src_j] + hr[i]); hlb bf16.
__global__ __launch_bounds__(256) void agg2_k(const ushort* __restrict__ hlb,
                                              const float* __restrict__ hr,
                                              const int* __restrict__ row_start,
                                              const int* __restrict__ csr_src,
                                              float* __restrict__ out) {
    int node = (blockIdx.x * blockDim.x + threadIdx.x) >> 6;
    int lane = threadIdx.x & 63;
    if (node >= NN) return;
    int c = lane & 15, g = lane >> 4;
    int beg = row_start[node], end = row_start[node + 1];
    float acc = 0.f;
    for (int j = beg + g; j < end; j += 4)
        acc += __builtin_bit_cast(float, (uint)hlb[(size_t)csr_src[j] * NC + c] << 16);
    acc += __shfl_xor(acc, 16);
    acc += __shfl_xor(acc, 32);
    float inv = 1.f / fmaxf((float)(end - beg), 1.f);
    float o = acc * inv + hr[(size_t)node * NC + c];
    float m = o;
#pragma unroll
    for (int d = 1; d < 16; d <<= 1) m = fmaxf(m, __shfl_xor(m, d));
    float e = expf(o - m);
    float s = e;
#pragma unroll
    for (int d = 1; d < 16; d <<= 1) s += __shfl_xor(s, d);
    float res = o - m - logf(s);
    if (lane < 16) out[(size_t)node * NC + c] = res;
}

// ---------------- launch ----------------

extern "C" void kernel_launch(void* const* d_in, const int* in_sizes, int n_in,
                              void* d_out, int out_size, void* d_ws, size_t ws_size,
                              hipStream_t stream) {
    const float* x   = (const float*)d_in[0];
    const int*   ei  = (const int*)d_in[1];
    const float* w1l = (const float*)d_in[2];
    const float* w1r = (const float*)d_in[3];
    const float* b1  = (const float*)d_in[4];
    const float* w2l = (const float*)d_in[5];
    const float* w2r = (const float*)d_in[6];
    const float* b2  = (const float*)d_in[7];
    float* out = (float*)d_out;
    const int* srcv = ei;        // edge_index[0]
    const int* dstv = ei + NE;   // edge_index[1]

    char* p = (char*)d_ws;
    auto carve = [&](size_t bytes) -> void* {
        void* r = (void*)p;
        p += (bytes + 255) & ~(size_t)255;
        return r;
    };
    uchar*  xl8       = (uchar*)carve((size_t)NN * D);                 // fp8
    float*  xr        = (float*)carve(sizeof(float) * (size_t)NN * D);
    ushort* hb        = (ushort*)carve(sizeof(ushort) * (size_t)NN * D); // bf16
    ushort* hlb       = (ushort*)carve(sizeof(ushort) * (size_t)NN * NC);// bf16
    float*  hr        = (float*)carve(sizeof(float) * (size_t)NN * NC);
    int*    csr_src   = (int*)carve(sizeof(int) * (size_t)NE);
    int*    row_start = (int*)carve(sizeof(int) * (NN + 32));
    int*    bucket_cnt    = (int*)carve(sizeof(int) * (NB + 32));
    int*    bucket_base   = (int*)carve(sizeof(int) * (NB + 32));
    int*    bucket_cursor = (int*)carve(sizeof(int) * (NB + 32));
    ushort* wtL       = (ushort*)carve(sizeof(ushort) * 2 * D * D);
    ushort* wtR       = (ushort*)carve(sizeof(ushort) * 2 * D * D);
    // ppack aliases hb (25.6 MB >= 6.4 MB): live only in disjoint phases
    // (ppack dead before agg1 writes hb; same-stream ordering sequences it).
    int*    ppack     = (int*)hb;

    hipMemsetAsync(bucket_cnt, 0, sizeof(int) * NB, stream);

    hist_k<<<256, 256, 0, stream>>>(dstv, bucket_cnt);
    scanb_k<<<1, 512, 0, stream>>>(bucket_cnt, bucket_base, bucket_cursor);
    part_k<<<(NE + EBLK - 1) / EBLK, 256, 0, stream>>>(srcv, dstv, bucket_cursor, ppack);
    fillcsr_k<<<NB, 256, 0, stream>>>(bucket_base, ppack, row_start, csr_src);

    prepw_k<<<128, 256, 0, stream>>>(w1l, w1r, wtL, wtR);
    mmL1_k<<<782, 512, 0, stream>>>(x, wtL, wtR, b1, xl8, xr);
    agg1_k<<<25000, 256, 0, stream>>>(xl8, xr, row_start, csr_src, (uint*)hb);

    mm16_k<<<1563, 256, 0, stream>>>(hb, w2l, w2r, b2, hlb, hr);
    agg2_k<<<25000, 256, 0, stream>>>(hlb, hr, row_start, csr_src, out);
}